// Round 1
// baseline (5007.713 us; speedup 1.0000x reference)
//
#include <hip/hip_runtime.h>

#define NU 100000
#define NI 150000
#define NTOT 250000
#define DD 64
#define NNZ_A 2000000
#define NNZ_S 800000

// ---------- elementwise init: all_emb = [(u1+u2)/2 ; item_emb]; out_final = all_emb ----------
__global__ void k_init(const float* __restrict__ u1, const float* __restrict__ u2,
                       const float* __restrict__ item, float* __restrict__ all_emb,
                       float* __restrict__ out_final) {
  int idx = blockIdx.x * blockDim.x + threadIdx.x;
  const int tot = NTOT * DD;
  const int nu = NU * DD;
  for (; idx < tot; idx += gridDim.x * blockDim.x) {
    float v;
    if (idx < nu) v = 0.5f * (u1[idx] + u2[idx]);
    else          v = item[idx - nu];
    all_emb[idx] = v;
    out_final[idx] = v;
  }
}

// ---------- gather negatives: u1n = u1[shuffle1], u2n = u2[shuffle2] ----------
__global__ void k_gather(const float* __restrict__ u1, const float* __restrict__ u2,
                         const int* __restrict__ s1, const int* __restrict__ s2,
                         float* __restrict__ u1n, float* __restrict__ u2n) {
  int idx = blockIdx.x * blockDim.x + threadIdx.x;
  const int tot = NU * DD;
  for (; idx < tot; idx += gridDim.x * blockDim.x) {
    int i = idx >> 6, j = idx & 63;
    u1n[idx] = u1[s1[i] * DD + j];
    u2n[idx] = u2[s2[i] * DD + j];
  }
}

// ---------- SpMM: Y[rows[e]] += vals[e] * X[cols[e]]  (one wave per nnz, lane = feature) ----------
__global__ void k_spmm_atomic(const int* __restrict__ rows, const int* __restrict__ cols,
                              const float* __restrict__ vals, const float* __restrict__ X,
                              float* __restrict__ Y, int nnz) {
  int lane = threadIdx.x & 63;
  int gw = (blockIdx.x * blockDim.x + threadIdx.x) >> 6;
  int nw = (gridDim.x * blockDim.x) >> 6;
  for (int e = gw; e < nnz; e += nw) {
    int r = rows[e];
    int c = cols[e];
    float v = vals[e];
    atomicAdd(&Y[r * DD + lane], v * X[c * DD + lane]);
  }
}

// ---------- out[i][j] = tanh(sum_k in[i][k] * W[j][k]) ; W is 64x64 row-major ----------
__global__ void k_gemm_tanh(const float* __restrict__ in, const float* __restrict__ W,
                            float* __restrict__ out, int nrows) {
  __shared__ float Wt[64 * 65];  // Wt[k*65 + j] = W[j][k], padded: conflict-free
  for (int idx = threadIdx.x; idx < 64 * 64; idx += blockDim.x) {
    int j = idx >> 6, k = idx & 63;
    Wt[k * 65 + j] = W[idx];
  }
  __syncthreads();
  int lane = threadIdx.x & 63;
  int wid = (blockIdx.x * blockDim.x + threadIdx.x) >> 6;
  int nw = (gridDim.x * blockDim.x) >> 6;
  for (int i = wid; i < nrows; i += nw) {
    float v = in[i * DD + lane];
    float acc = 0.f;
#pragma unroll
    for (int k = 0; k < 64; ++k)
      acc = fmaf(__shfl(v, k), Wt[k * 65 + lane], acc);
    out[i * DD + lane] = tanhf(acc);
  }
}

// ---------- column sums (raw, scaled later): csum[j] += sum_i x[i][j] ----------
__global__ void k_colsum(const float* __restrict__ x, float* __restrict__ csum, int nrows) {
  int lane = threadIdx.x & 63;
  int wid = (blockIdx.x * blockDim.x + threadIdx.x) >> 6;
  int nw = (gridDim.x * blockDim.x) >> 6;
  float acc = 0.f;
  for (int i = wid; i < nrows; i += nw) acc += x[i * DD + lane];
  atomicAdd(&csum[lane], acc);
}

// ---------- w = fk_W @ (csum/NU)  for both c1,c2 ----------
__global__ void k_wvec(const float* __restrict__ fkW, const float* __restrict__ c1r,
                       const float* __restrict__ c2r, float* __restrict__ w1,
                       float* __restrict__ w2) {
  int j = threadIdx.x;  // 64 threads
  float a1 = 0.f, a2 = 0.f;
  for (int k = 0; k < 64; ++k) {
    float w = fkW[j * 64 + k];
    a1 += w * c1r[k];
    a2 += w * c2r[k];
  }
  w1[j] = a1 * (1.0f / NU);
  w2[j] = a2 * (1.0f / NU);
}

// ---------- logits: for i in [0,2NU): dot(row, w) + b -> out[i*6 + slot_base + {0..nslots-1}] ----------
__global__ void k_logits(const float* __restrict__ xa, const float* __restrict__ xb,
                         const float* __restrict__ w1, const float* __restrict__ w2,
                         const float* __restrict__ fkb, float* __restrict__ out_logits,
                         int slot_base, int nslots) {
  int lane = threadIdx.x & 63;
  int wid = (blockIdx.x * blockDim.x + threadIdx.x) >> 6;
  int nw = (gridDim.x * blockDim.x) >> 6;
  float b = fkb[0];
  for (int i = wid; i < 2 * NU; i += nw) {
    const float* xrow;
    float wv;
    if (i < NU) { xrow = xa + (size_t)i * DD;        wv = w1[lane]; }
    else        { xrow = xb + (size_t)(i - NU) * DD; wv = w2[lane]; }
    float p = xrow[lane] * wv;
#pragma unroll
    for (int off = 32; off > 0; off >>= 1) p += __shfl_xor(p, off);
    if (lane == 0) {
      float val = p + b;
      for (int s = 0; s < nslots; ++s) out_logits[(size_t)i * 6 + slot_base + s] = val;
    }
  }
}

// ---------- items: all_emb[NU:] = agg[NU:]; out_final[NU:] += agg[NU:] ----------
__global__ void k_items(const float* __restrict__ agg, float* __restrict__ all_emb,
                        float* __restrict__ out_final) {
  int idx = blockIdx.x * blockDim.x + threadIdx.x;
  const int tot = NI * DD;
  for (; idx < tot; idx += gridDim.x * blockDim.x) {
    float v = agg[NU * DD + idx];
    all_emb[NU * DD + idx] = v;
    out_final[NU * DD + idx] += v;
  }
}

// ---------- users_raw = [u_next, 0.5(u1s+u2s)] @ Ws.T ; also accumulate sum of squares ----------
__global__ void k_users(const float* __restrict__ u_next, const float* __restrict__ u1s,
                        const float* __restrict__ u2s, const float* __restrict__ Ws,
                        float* __restrict__ users_raw, float* __restrict__ sumsq) {
  __shared__ float Wt[128 * 65];  // Wt[k*65 + j] = Ws[j][k], j<64, k<128
  for (int idx = threadIdx.x; idx < 64 * 128; idx += blockDim.x) {
    int j = idx >> 7, k = idx & 127;
    Wt[k * 65 + j] = Ws[idx];
  }
  __syncthreads();
  int lane = threadIdx.x & 63;
  int wid = (blockIdx.x * blockDim.x + threadIdx.x) >> 6;
  int nw = (gridDim.x * blockDim.x) >> 6;
  float ss = 0.f;
  for (int i = wid; i < NU; i += nw) {
    float va = u_next[i * DD + lane];
    float vb = 0.5f * (u1s[i * DD + lane] + u2s[i * DD + lane]);
    float acc = 0.f;
#pragma unroll
    for (int k = 0; k < 64; ++k)
      acc = fmaf(__shfl(va, k), Wt[k * 65 + lane], acc);
#pragma unroll
    for (int k = 0; k < 64; ++k)
      acc = fmaf(__shfl(vb, k), Wt[(64 + k) * 65 + lane], acc);
    users_raw[i * DD + lane] = acc;
    ss += acc * acc;
  }
#pragma unroll
  for (int off = 32; off > 0; off >>= 1) ss += __shfl_xor(ss, off);
  if (lane == 0) atomicAdd(sumsq, ss);
}

// ---------- out_final[:NU] += users_raw / ||users_raw||_F ----------
__global__ void k_users_acc(const float* __restrict__ users_raw,
                            const float* __restrict__ sumsq, float* __restrict__ out_final) {
  float scale = 1.0f / sqrtf(*sumsq);
  int idx = blockIdx.x * blockDim.x + threadIdx.x;
  for (; idx < NU * DD; idx += gridDim.x * blockDim.x)
    out_final[idx] += users_raw[idx] * scale;
}

// ---------- final scale by 1/4 ----------
__global__ void k_scale(float* __restrict__ out_final) {
  int idx = blockIdx.x * blockDim.x + threadIdx.x;
  const int tot = NTOT * DD;
  for (; idx < tot; idx += gridDim.x * blockDim.x) out_final[idx] *= 0.25f;
}

extern "C" void kernel_launch(void* const* d_in, const int* in_sizes, int n_in,
                              void* d_out, int out_size, void* d_ws, size_t ws_size,
                              hipStream_t stream) {
  const float* u1      = (const float*)d_in[0];
  const float* u2      = (const float*)d_in[1];
  const float* item    = (const float*)d_in[2];
  const float* Wi      = (const float*)d_in[3];
  const float* Wc      = (const float*)d_in[4];
  const float* Ws      = (const float*)d_in[5];
  const float* fk_W    = (const float*)d_in[6];
  const float* fk_b    = (const float*)d_in[7];
  const float* A_vals  = (const float*)d_in[8];
  const float* A2_vals = (const float*)d_in[9];
  const float* S_vals  = (const float*)d_in[10];
  const int*   A_rows  = (const int*)d_in[11];
  const int*   A_cols  = (const int*)d_in[12];
  const int*   A2_rows = (const int*)d_in[13];
  const int*   A2_cols = (const int*)d_in[14];
  const int*   S_rows  = (const int*)d_in[15];
  const int*   S_cols  = (const int*)d_in[16];
  const int*   sh1     = (const int*)d_in[17];
  const int*   sh2     = (const int*)d_in[18];

  float* ws = (float*)d_ws;
  float* all_emb = ws;                       // NTOT*64
  float* agg     = all_emb + NTOT * DD;      // NTOT*64
  float* tmp     = agg;                      // alias: first NU*64 of agg (safe: agg[:NU] consumed before tmp reuse)
  float* u1_soc  = agg + NTOT * DD;          // NU*64
  float* u2_soc  = u1_soc + NU * DD;
  float* u1_neg  = u2_soc + NU * DD;
  float* u2_neg  = u1_neg + NU * DD;
  float* c1r     = u2_neg + NU * DD;         // 64
  float* c2r     = c1r + 64;                 // 64
  float* w1      = c2r + 64;                 // 64
  float* w2      = w1 + 64;                  // 64
  float* sumsq   = w2 + 64;                  // 1

  float* out        = (float*)d_out;
  float* out_logits = out + NTOT * DD;

  // init
  hipMemsetAsync(c1r, 0, 128 * sizeof(float), stream);
  k_init<<<2048, 256, 0, stream>>>(u1, u2, item, all_emb, out);
  k_gather<<<1024, 256, 0, stream>>>(u1, u2, sh1, sh2, u1_neg, u2_neg);

  // loop-invariant social embeddings (computed once)
  hipMemsetAsync(tmp, 0, (size_t)NU * DD * sizeof(float), stream);
  k_spmm_atomic<<<2048, 256, 0, stream>>>(S_rows, S_cols, S_vals, u1, tmp, NNZ_S);
  k_gemm_tanh<<<1024, 256, 0, stream>>>(tmp, Wc, u1_soc, NU);
  hipMemsetAsync(tmp, 0, (size_t)NU * DD * sizeof(float), stream);
  k_spmm_atomic<<<2048, 256, 0, stream>>>(S_rows, S_cols, S_vals, u2, tmp, NNZ_S);
  k_gemm_tanh<<<1024, 256, 0, stream>>>(tmp, Wc, u2_soc, NU);

  k_colsum<<<256, 256, 0, stream>>>(u1_soc, c1r, NU);
  k_colsum<<<256, 256, 0, stream>>>(u2_soc, c2r, NU);
  k_wvec<<<1, 64, 0, stream>>>(fk_W, c1r, c2r, w1, w2);

  // logits_true (identical for all 3 layers): sc1 = u2_soc . w1 ; sc2 = u1_soc . w2
  k_logits<<<1024, 256, 0, stream>>>(u2_soc, u1_soc, w1, w2, fk_b, out_logits, 0, 3);

  for (int l = 0; l < 3; ++l) {
    const int*   rows = (l == 0) ? A_rows : A2_rows;
    const int*   cols = (l == 0) ? A_cols : A2_cols;
    const float* vals = (l == 0) ? A_vals : A2_vals;

    hipMemsetAsync(agg, 0, (size_t)NTOT * DD * sizeof(float), stream);
    k_spmm_atomic<<<4096, 256, 0, stream>>>(rows, cols, vals, all_emb, agg, NNZ_A);
    // u_next = tanh(agg[:NU] @ Wi.T) -> all_emb[:NU]
    k_gemm_tanh<<<1024, 256, 0, stream>>>(agg, Wi, all_emb, NU);
    // items_next -> all_emb[NU:], accumulate into out_final
    k_items<<<2048, 256, 0, stream>>>(agg, all_emb, out);

    // negative branch (recursive)
    hipMemsetAsync(tmp, 0, (size_t)NU * DD * sizeof(float), stream);
    k_spmm_atomic<<<2048, 256, 0, stream>>>(S_rows, S_cols, S_vals, u1_neg, tmp, NNZ_S);
    k_gemm_tanh<<<1024, 256, 0, stream>>>(tmp, Wc, u1_neg, NU);
    hipMemsetAsync(tmp, 0, (size_t)NU * DD * sizeof(float), stream);
    k_spmm_atomic<<<2048, 256, 0, stream>>>(S_rows, S_cols, S_vals, u2_neg, tmp, NNZ_S);
    k_gemm_tanh<<<1024, 256, 0, stream>>>(tmp, Wc, u2_neg, NU);

    // logits_false for this layer: sc3 = u2_neg . w1 ; sc4 = u1_neg . w2
    k_logits<<<1024, 256, 0, stream>>>(u2_neg, u1_neg, w1, w2, fk_b, out_logits, 3 + l, 1);

    // users = [u_next, 0.5(u1_soc+u2_soc)] @ Ws.T, normalized by Frobenius norm, accumulated
    hipMemsetAsync(sumsq, 0, sizeof(float), stream);
    k_users<<<1024, 256, 0, stream>>>(all_emb, u1_soc, u2_soc, Ws, tmp, sumsq);
    k_users_acc<<<2048, 256, 0, stream>>>(tmp, sumsq, out);
  }

  k_scale<<<2048, 256, 0, stream>>>(out);
}

// Round 3
// 3036.282 us; speedup vs baseline: 1.6493x; 1.6493x over previous
//
#include <hip/hip_runtime.h>

#define NU 100000
#define NI 150000
#define NTOT 250000
#define DD 64
#define NNZ_A 2000000
#define NNZ_S 800000
#define SCAN_CHUNK 2048  // 256 threads x 8

// ---------- init: all_emb = [(u1+u2)/2 ; item_emb]; out_final = all_emb ----------
__global__ void k_init(const float* __restrict__ u1, const float* __restrict__ u2,
                       const float* __restrict__ item, float* __restrict__ all_emb,
                       float* __restrict__ out_final) {
  int idx = blockIdx.x * blockDim.x + threadIdx.x;
  const int tot = NTOT * DD;
  const int nu = NU * DD;
  for (; idx < tot; idx += gridDim.x * blockDim.x) {
    float v;
    if (idx < nu) v = 0.5f * (u1[idx] + u2[idx]);
    else          v = item[idx - nu];
    all_emb[idx] = v;
    out_final[idx] = v;
  }
}

// ---------- gather negatives ----------
__global__ void k_gather(const float* __restrict__ u1, const float* __restrict__ u2,
                         const int* __restrict__ s1, const int* __restrict__ s2,
                         float* __restrict__ u1n, float* __restrict__ u2n) {
  int idx = blockIdx.x * blockDim.x + threadIdx.x;
  const int tot = NU * DD;
  for (; idx < tot; idx += gridDim.x * blockDim.x) {
    int i = idx >> 6, j = idx & 63;
    u1n[idx] = u1[s1[i] * DD + j];
    u2n[idx] = u2[s2[i] * DD + j];
  }
}

// ================= CSR build (counting sort) =================
__global__ void k_hist(const int* __restrict__ rows, int* __restrict__ cnt, int nnz) {
  int idx = blockIdx.x * blockDim.x + threadIdx.x;
  for (; idx < nnz; idx += gridDim.x * blockDim.x)
    atomicAdd(&cnt[rows[idx]], 1);
}

__global__ void k_scan1(const int* __restrict__ cnt, int* __restrict__ bsum, int n) {
  __shared__ int sdata[256];
  int base = blockIdx.x * SCAN_CHUNK;
  int s = 0;
#pragma unroll
  for (int k = 0; k < 8; ++k) {
    int i = base + threadIdx.x * 8 + k;
    s += (i < n) ? cnt[i] : 0;
  }
  sdata[threadIdx.x] = s;
  __syncthreads();
  for (int off = 128; off > 0; off >>= 1) {
    if (threadIdx.x < off) sdata[threadIdx.x] += sdata[threadIdx.x + off];
    __syncthreads();
  }
  if (threadIdx.x == 0) bsum[blockIdx.x] = sdata[0];
}

// single block: exclusive scan of bsum in place (nb <= 256)
__global__ void k_scan2(int* bsum, int nb) {
  __shared__ int sdata[256];
  int v = (threadIdx.x < nb) ? bsum[threadIdx.x] : 0;
  sdata[threadIdx.x] = v;
  __syncthreads();
  for (int off = 1; off < 256; off <<= 1) {
    int t = (threadIdx.x >= (unsigned)off) ? sdata[threadIdx.x - off] : 0;
    __syncthreads();
    sdata[threadIdx.x] += t;
    __syncthreads();
  }
  if (threadIdx.x < nb) bsum[threadIdx.x] = sdata[threadIdx.x] - v;
}

// writes rowptr[0..n] and cursor cur[0..n-1]; cnt aliases cur (read-then-write same thread)
__global__ void k_scan3(const int* __restrict__ cnt, const int* __restrict__ bsum,
                        int* __restrict__ rowptr, int* __restrict__ cur, int n, int nnz) {
  __shared__ int sdata[256];
  int base = blockIdx.x * SCAN_CHUNK;
  int loc[8];
  int s = 0;
#pragma unroll
  for (int k = 0; k < 8; ++k) {
    int i = base + threadIdx.x * 8 + k;
    loc[k] = (i < n) ? cnt[i] : 0;
    s += loc[k];
  }
  sdata[threadIdx.x] = s;
  __syncthreads();
  for (int off = 1; off < 256; off <<= 1) {
    int t = (threadIdx.x >= (unsigned)off) ? sdata[threadIdx.x - off] : 0;
    __syncthreads();
    sdata[threadIdx.x] += t;
    __syncthreads();
  }
  int pre = bsum[blockIdx.x] + sdata[threadIdx.x] - s;  // exclusive prefix
#pragma unroll
  for (int k = 0; k < 8; ++k) {
    int i = base + threadIdx.x * 8 + k;
    if (i < n) { rowptr[i] = pre; cur[i] = pre; pre += loc[k]; }
  }
  if (blockIdx.x == 0 && threadIdx.x == 0) rowptr[n] = nnz;
}

__global__ void k_scatter(const int* __restrict__ rows, const int* __restrict__ cols,
                          const float* __restrict__ vals, int* __restrict__ cur,
                          int2* __restrict__ cv, int nnz) {
  int idx = blockIdx.x * blockDim.x + threadIdx.x;
  for (; idx < nnz; idx += gridDim.x * blockDim.x) {
    int r = rows[idx];
    int p = atomicAdd(&cur[r], 1);
    cv[p] = make_int2(cols[idx], __float_as_int(vals[idx]));
  }
}

// ================= fused CSR SpMM kernels =================
// A-type: wave per row. r<NU: embNext=tanh(acc@Wi.T); r>=NU: embNext=acc, outF+=acc
__global__ void k_spmm_fusedA(const int* __restrict__ rowptr, const int2* __restrict__ cv,
                              const float* __restrict__ X, const float* __restrict__ W,
                              float* __restrict__ embNext, float* __restrict__ outF) {
  __shared__ float Wt[64 * 65];
  for (int idx = threadIdx.x; idx < 64 * 64; idx += blockDim.x)
    Wt[(idx & 63) * 65 + (idx >> 6)] = W[idx];
  __syncthreads();
  int lane = threadIdx.x & 63;
  int wid = (blockIdx.x * blockDim.x + threadIdx.x) >> 6;
  int nw = (gridDim.x * blockDim.x) >> 6;
  for (int r = wid; r < NTOT; r += nw) {
    int start = rowptr[r], end = rowptr[r + 1];
    float acc = 0.f;
    for (int p0 = start; p0 < end; p0 += 64) {
      int n = min(64, end - p0);
      int2 e = cv[p0 + (lane < n ? lane : 0)];
      for (int k = 0; k < n; ++k) {
        int c = __shfl(e.x, k);
        float v = __int_as_float(__shfl(e.y, k));
        acc = fmaf(v, X[c * DD + lane], acc);
      }
    }
    if (r < NU) {
      float o = 0.f;
#pragma unroll
      for (int k = 0; k < 64; ++k) o = fmaf(__shfl(acc, k), Wt[k * 65 + lane], o);
      embNext[r * DD + lane] = tanhf(o);
    } else {
      embNext[r * DD + lane] = acc;
      outF[r * DD + lane] += acc;
    }
  }
}

// S-type: wave per row r<NU. t = tanh(acc@Wc.T) -> xout. If wvec: logit to slot.
__global__ void k_spmm_fusedS(const int* __restrict__ rowptr, const int2* __restrict__ cv,
                              const float* __restrict__ xin, const float* __restrict__ W,
                              float* __restrict__ xout, const float* __restrict__ wvec,
                              const float* __restrict__ fkb, float* __restrict__ out_logits,
                              int base, int slot) {
  __shared__ float Wt[64 * 65];
  for (int idx = threadIdx.x; idx < 64 * 64; idx += blockDim.x)
    Wt[(idx & 63) * 65 + (idx >> 6)] = W[idx];
  __syncthreads();
  int lane = threadIdx.x & 63;
  int wid = (blockIdx.x * blockDim.x + threadIdx.x) >> 6;
  int nw = (gridDim.x * blockDim.x) >> 6;
  float wv = wvec ? wvec[lane] : 0.f;
  for (int r = wid; r < NU; r += nw) {
    int start = rowptr[r], end = rowptr[r + 1];
    float acc = 0.f;
    for (int p0 = start; p0 < end; p0 += 64) {
      int n = min(64, end - p0);
      int2 e = cv[p0 + (lane < n ? lane : 0)];
      for (int k = 0; k < n; ++k) {
        int c = __shfl(e.x, k);
        float v = __int_as_float(__shfl(e.y, k));
        acc = fmaf(v, xin[c * DD + lane], acc);
      }
    }
    float o = 0.f;
#pragma unroll
    for (int k = 0; k < 64; ++k) o = fmaf(__shfl(acc, k), Wt[k * 65 + lane], o);
    float t = tanhf(o);
    xout[r * DD + lane] = t;
    if (wvec) {
      float p = t * wv;
#pragma unroll
      for (int off = 32; off > 0; off >>= 1) p += __shfl_xor(p, off);
      if (lane == 0) out_logits[(size_t)(base + r) * 6 + slot] = p + fkb[0];
    }
  }
}

// ---------- column sums ----------
__global__ void k_colsum(const float* __restrict__ x, float* __restrict__ csum, int nrows) {
  int lane = threadIdx.x & 63;
  int wid = (blockIdx.x * blockDim.x + threadIdx.x) >> 6;
  int nw = (gridDim.x * blockDim.x) >> 6;
  float acc = 0.f;
  for (int i = wid; i < nrows; i += nw) acc += x[i * DD + lane];
  atomicAdd(&csum[lane], acc);
}

// ---------- w = fk_W @ (csum/NU) ----------
__global__ void k_wvec(const float* __restrict__ fkW, const float* __restrict__ c1r,
                       const float* __restrict__ c2r, float* __restrict__ w1,
                       float* __restrict__ w2) {
  int j = threadIdx.x;
  float a1 = 0.f, a2 = 0.f;
  for (int k = 0; k < 64; ++k) {
    float w = fkW[j * 64 + k];
    a1 += w * c1r[k];
    a2 += w * c2r[k];
  }
  w1[j] = a1 * (1.0f / NU);
  w2[j] = a2 * (1.0f / NU);
}

// ---------- true logits (identical across the 3 layers) ----------
__global__ void k_logits(const float* __restrict__ xa, const float* __restrict__ xb,
                         const float* __restrict__ w1, const float* __restrict__ w2,
                         const float* __restrict__ fkb, float* __restrict__ out_logits,
                         int slot_base, int nslots) {
  int lane = threadIdx.x & 63;
  int wid = (blockIdx.x * blockDim.x + threadIdx.x) >> 6;
  int nw = (gridDim.x * blockDim.x) >> 6;
  float b = fkb[0];
  for (int i = wid; i < 2 * NU; i += nw) {
    const float* xrow;
    float wv;
    if (i < NU) { xrow = xa + (size_t)i * DD;        wv = w1[lane]; }
    else        { xrow = xb + (size_t)(i - NU) * DD; wv = w2[lane]; }
    float p = xrow[lane] * wv;
#pragma unroll
    for (int off = 32; off > 0; off >>= 1) p += __shfl_xor(p, off);
    if (lane == 0) {
      float val = p + b;
      for (int s = 0; s < nslots; ++s) out_logits[(size_t)i * 6 + slot_base + s] = val;
    }
  }
}

// ---------- UC[i] = (0.5*(UC[i]+V[i])) @ Ws[:,64:].T  (in-place, wave-per-row) ----------
__global__ void k_comb_gemm(float* __restrict__ uc, const float* __restrict__ v,
                            const float* __restrict__ Ws) {
  __shared__ float Wt[64 * 65];
  for (int idx = threadIdx.x; idx < 64 * 64; idx += blockDim.x) {
    int j = idx >> 6, k = idx & 63;
    Wt[k * 65 + j] = Ws[j * 128 + 64 + k];
  }
  __syncthreads();
  int lane = threadIdx.x & 63;
  int wid = (blockIdx.x * blockDim.x + threadIdx.x) >> 6;
  int nw = (gridDim.x * blockDim.x) >> 6;
  for (int i = wid; i < NU; i += nw) {
    float c = 0.5f * (uc[i * DD + lane] + v[i * DD + lane]);
    float acc = 0.f;
#pragma unroll
    for (int k = 0; k < 64; ++k) acc = fmaf(__shfl(c, k), Wt[k * 65 + lane], acc);
    uc[i * DD + lane] = acc;
  }
}

// ---------- users_raw = u_next @ Ws[:,:64].T + UC ; sum of squares ----------
__global__ void k_users(const float* __restrict__ u_next, const float* __restrict__ uc,
                        const float* __restrict__ Ws, float* __restrict__ users_raw,
                        float* __restrict__ sumsq) {
  __shared__ float Wt[64 * 65];
  for (int idx = threadIdx.x; idx < 64 * 64; idx += blockDim.x) {
    int j = idx >> 6, k = idx & 63;
    Wt[k * 65 + j] = Ws[j * 128 + k];
  }
  __syncthreads();
  int lane = threadIdx.x & 63;
  int wid = (blockIdx.x * blockDim.x + threadIdx.x) >> 6;
  int nw = (gridDim.x * blockDim.x) >> 6;
  float ss = 0.f;
  for (int i = wid; i < NU; i += nw) {
    float va = u_next[i * DD + lane];
    float acc = uc[i * DD + lane];
#pragma unroll
    for (int k = 0; k < 64; ++k) acc = fmaf(__shfl(va, k), Wt[k * 65 + lane], acc);
    users_raw[i * DD + lane] = acc;
    ss += acc * acc;
  }
#pragma unroll
  for (int off = 32; off > 0; off >>= 1) ss += __shfl_xor(ss, off);
  if (lane == 0) atomicAdd(sumsq, ss);
}

__global__ void k_users_acc(const float* __restrict__ users_raw,
                            const float* __restrict__ sumsq, float* __restrict__ out_final) {
  float scale = 1.0f / sqrtf(*sumsq);
  int idx = blockIdx.x * blockDim.x + threadIdx.x;
  for (; idx < NU * DD; idx += gridDim.x * blockDim.x)
    out_final[idx] += users_raw[idx] * scale;
}

__global__ void k_scale(float* __restrict__ out_final) {
  int idx = blockIdx.x * blockDim.x + threadIdx.x;
  const int tot = NTOT * DD;
  for (; idx < tot; idx += gridDim.x * blockDim.x) out_final[idx] *= 0.25f;
}

extern "C" void kernel_launch(void* const* d_in, const int* in_sizes, int n_in,
                              void* d_out, int out_size, void* d_ws, size_t ws_size,
                              hipStream_t stream) {
  const float* u1      = (const float*)d_in[0];
  const float* u2      = (const float*)d_in[1];
  const float* item    = (const float*)d_in[2];
  const float* Wi      = (const float*)d_in[3];
  const float* Wc      = (const float*)d_in[4];
  const float* Ws      = (const float*)d_in[5];
  const float* fk_W    = (const float*)d_in[6];
  const float* fk_b    = (const float*)d_in[7];
  const float* A_vals  = (const float*)d_in[8];
  const float* A2_vals = (const float*)d_in[9];
  const float* S_vals  = (const float*)d_in[10];
  const int*   A_rows  = (const int*)d_in[11];
  const int*   A_cols  = (const int*)d_in[12];
  const int*   A2_rows = (const int*)d_in[13];
  const int*   A2_cols = (const int*)d_in[14];
  const int*   S_rows  = (const int*)d_in[15];
  const int*   S_cols  = (const int*)d_in[16];
  const int*   sh1     = (const int*)d_in[17];
  const int*   sh2     = (const int*)d_in[18];

  // ---- workspace: 57,400,515 floats = 229.6 MB (< proven-safe 230.4 MB) ----
  float* ws   = (float*)d_ws;
  float* embA = ws;                              // 16,000,000
  float* embB = embA + (size_t)NTOT * DD;        // 16,000,000
  float* UC   = embB + (size_t)NTOT * DD;        // 6,400,000 (u1_soc -> comb@Ws2.T)
  float* n1   = UC + (size_t)NU * DD;            // 6,400,000 (u1_neg)
  float* n2   = n1 + (size_t)NU * DD;            // 6,400,000 (u2_neg)
  int2*  cvA  = (int2*)(n2 + (size_t)NU * DD);   // 2,000,000 int2 (A, then A2)
  int2*  cvS  = cvA + NNZ_A;                     // 800,000 int2
  int*   ptrA = (int*)(cvS + NNZ_S);             // 250,001
  int*   ptrS = ptrA + (NTOT + 1);               // 100,001
  int*   cur  = ptrS + (NU + 1);                 // 250,000
  int*   bsum = cur + NTOT;                      // 256
  float* c1r  = (float*)(bsum + 256);            // 64
  float* c2r  = c1r + 64;
  float* w1   = c2r + 64;
  float* w2   = w1 + 64;
  float* sumsq = w2 + 64;                        // 1

  float* out        = (float*)d_out;
  float* out_logits = out + (size_t)NTOT * DD;

  auto build = [&](const int* rows, const int* cols, const float* vals,
                   int n, int nnz, int* ptr, int2* cv) {
    int nb = (n + SCAN_CHUNK - 1) / SCAN_CHUNK;
    hipMemsetAsync(cur, 0, (size_t)n * sizeof(int), stream);
    k_hist<<<2048, 256, 0, stream>>>(rows, cur, nnz);
    k_scan1<<<nb, 256, 0, stream>>>(cur, bsum, n);
    k_scan2<<<1, 256, 0, stream>>>(bsum, nb);
    k_scan3<<<nb, 256, 0, stream>>>(cur, bsum, ptr, cur, n, nnz);
    k_scatter<<<2048, 256, 0, stream>>>(rows, cols, vals, cur, cv, nnz);
  };

  // ---------- CSR for S and A (A2 rebuilt in-place after layer 0) ----------
  build(S_rows, S_cols, S_vals, NU, NNZ_S, ptrS, cvS);
  build(A_rows, A_cols, A_vals, NTOT, NNZ_A, ptrA, cvA);

  // ---------- init ----------
  hipMemsetAsync(c1r, 0, 128 * sizeof(float), stream);
  k_init<<<2048, 256, 0, stream>>>(u1, u2, item, embA, out);
  k_gather<<<1024, 256, 0, stream>>>(u1, u2, sh1, sh2, n1, n2);

  // ---------- loop-invariant socials: u1_soc -> UC, u2_soc -> embB (free pre-loop) ----------
  k_spmm_fusedS<<<2048, 256, 0, stream>>>(ptrS, cvS, u1, Wc, UC, nullptr, fk_b, out_logits, 0, 0);
  k_spmm_fusedS<<<2048, 256, 0, stream>>>(ptrS, cvS, u2, Wc, embB, nullptr, fk_b, out_logits, 0, 0);
  k_colsum<<<256, 256, 0, stream>>>(UC, c1r, NU);     // c1 from u1_soc
  k_colsum<<<256, 256, 0, stream>>>(embB, c2r, NU);   // c2 from u2_soc
  k_wvec<<<1, 64, 0, stream>>>(fk_W, c1r, c2r, w1, w2);
  // sc1 = u2_soc.w1 (rows [0,NU)), sc2 = u1_soc.w2 (rows [NU,2NU)), slots 0..2
  k_logits<<<1024, 256, 0, stream>>>(embB, UC, w1, w2, fk_b, out_logits, 0, 3);
  // UC := (0.5*(u1_soc+u2_soc)) @ Ws[:,64:].T   (loop-invariant half of k_users)
  k_comb_gemm<<<1024, 256, 0, stream>>>(UC, embB, Ws);

  float* embCur = embA;
  float* embNext = embB;
  float* negA = n1;  // u1_neg
  float* negB = n2;  // u2_neg
  for (int l = 0; l < 3; ++l) {
    // fused: agg + tanh(agg@Wi.T) for users + item passthrough/out-accumulate
    k_spmm_fusedA<<<4096, 256, 0, stream>>>(ptrA, cvA, embCur, Wi, embNext, out);
    if (l == 0)  // A consumed; rebuild buffer with A2 for layers 1,2
      build(A2_rows, A2_cols, A2_vals, NTOT, NNZ_A, ptrA, cvA);

    float* F = embCur;  // dead after fusedA: scratch region (NTOT*64 floats)
    // new u1_neg -> F[0:NU*64]; sc4 = u1_neg_new . w2, rows [NU,2NU), slot 3+l
    k_spmm_fusedS<<<2048, 256, 0, stream>>>(ptrS, cvS, negA, Wc, F, w2, fk_b,
                                            out_logits, NU, 3 + l);
    // new u2_neg -> negA (old u1_neg dead); sc3 = u2_neg_new . w1, rows [0,NU), slot 3+l
    k_spmm_fusedS<<<2048, 256, 0, stream>>>(ptrS, cvS, negB, Wc, negA, w1, fk_b,
                                            out_logits, 0, 3 + l);

    // users_raw = u_next@Ws1.T + UC -> F[NU*64:2*NU*64]; normalize+accumulate
    hipMemsetAsync(sumsq, 0, sizeof(float), stream);
    k_users<<<1024, 256, 0, stream>>>(embNext, UC, Ws, F + (size_t)NU * DD, sumsq);
    k_users_acc<<<2048, 256, 0, stream>>>(F + (size_t)NU * DD, sumsq, out);

    // restore ping-pong invariant: new u1_neg -> negB, then swap names
    hipMemcpyAsync(negB, F, (size_t)NU * DD * sizeof(float),
                   hipMemcpyDeviceToDevice, stream);
    { float* t = negA; negA = negB; negB = t; }   // negA=u1_neg, negB=u2_neg
    { float* t = embCur; embCur = embNext; embNext = t; }
  }

  k_scale<<<2048, 256, 0, stream>>>(out);
}

// Round 4
// 2696.011 us; speedup vs baseline: 1.8575x; 1.1262x over previous
//
#include <hip/hip_runtime.h>

#define NU 100000
#define NI 150000
#define NTOT 250000
#define DD 64
#define NNZ_A 2000000
#define NNZ_S 800000
#define SCAN_CHUNK 2048  // 256 threads x 8

// ================= shared device helpers =================
// CSR row gather: acc[lane] = sum_e vals[e] * X[cols[e]*64 + lane]
// 8-way batched loads: 8 independent global_loads in flight per wave (MLP fix).
__device__ __forceinline__ float row_gather(const int* __restrict__ rowptr,
                                            const int2* __restrict__ cv,
                                            const float* __restrict__ X,
                                            int r, int lane) {
  int start = rowptr[r], end = rowptr[r + 1];
  float acc = 0.f;
  for (int p0 = start; p0 < end; p0 += 64) {
    int n = min(64, end - p0);
    int2 e = cv[p0 + (lane < n ? lane : 0)];
    for (int k = 0; k < n; k += 8) {
      float x[8], vv[8];
#pragma unroll
      for (int u = 0; u < 8; ++u) {
        int kk = k + u;
        int ks = min(kk, n - 1);                      // clamp (wave-uniform)
        int c = __shfl(e.x, ks);
        vv[u] = (kk < n) ? __int_as_float(__shfl(e.y, ks)) : 0.f;  // pad v=0
        x[u] = X[(size_t)c * DD + lane];              // 8 loads issue back-to-back
      }
#pragma unroll
      for (int u = 0; u < 8; ++u) acc = fmaf(vv[u], x[u], acc);
    }
  }
  return acc;
}

// o[lane] = sum_k acc_bcast[k] * Wt[k*65 + lane]
__device__ __forceinline__ float gemm64(float acc, const float* Wt, int lane) {
  float o = 0.f;
#pragma unroll
  for (int k = 0; k < 64; ++k) o = fmaf(__shfl(acc, k), Wt[k * 65 + lane], o);
  return o;
}

// ---------- init: all_emb = [(u1+u2)/2 ; item_emb]; out_final = all_emb ----------
__global__ void k_init(const float* __restrict__ u1, const float* __restrict__ u2,
                       const float* __restrict__ item, float* __restrict__ all_emb,
                       float* __restrict__ out_final) {
  int idx = blockIdx.x * blockDim.x + threadIdx.x;
  const int tot = NTOT * DD;
  const int nu = NU * DD;
  for (; idx < tot; idx += gridDim.x * blockDim.x) {
    float v;
    if (idx < nu) v = 0.5f * (u1[idx] + u2[idx]);
    else          v = item[idx - nu];
    all_emb[idx] = v;
    out_final[idx] = v;
  }
}

// ---------- gather negatives ----------
__global__ void k_gather(const float* __restrict__ u1, const float* __restrict__ u2,
                         const int* __restrict__ s1, const int* __restrict__ s2,
                         float* __restrict__ u1n, float* __restrict__ u2n) {
  int idx = blockIdx.x * blockDim.x + threadIdx.x;
  const int tot = NU * DD;
  for (; idx < tot; idx += gridDim.x * blockDim.x) {
    int i = idx >> 6, j = idx & 63;
    u1n[idx] = u1[s1[i] * DD + j];
    u2n[idx] = u2[s2[i] * DD + j];
  }
}

// ================= CSR build (counting sort) =================
__global__ void k_hist(const int* __restrict__ rows, int* __restrict__ cnt, int nnz) {
  int idx = blockIdx.x * blockDim.x + threadIdx.x;
  for (; idx < nnz; idx += gridDim.x * blockDim.x)
    atomicAdd(&cnt[rows[idx]], 1);
}

__global__ void k_scan1(const int* __restrict__ cnt, int* __restrict__ bsum, int n) {
  __shared__ int sdata[256];
  int base = blockIdx.x * SCAN_CHUNK;
  int s = 0;
#pragma unroll
  for (int k = 0; k < 8; ++k) {
    int i = base + threadIdx.x * 8 + k;
    s += (i < n) ? cnt[i] : 0;
  }
  sdata[threadIdx.x] = s;
  __syncthreads();
  for (int off = 128; off > 0; off >>= 1) {
    if (threadIdx.x < off) sdata[threadIdx.x] += sdata[threadIdx.x + off];
    __syncthreads();
  }
  if (threadIdx.x == 0) bsum[blockIdx.x] = sdata[0];
}

__global__ void k_scan2(int* bsum, int nb) {
  __shared__ int sdata[256];
  int v = (threadIdx.x < nb) ? bsum[threadIdx.x] : 0;
  sdata[threadIdx.x] = v;
  __syncthreads();
  for (int off = 1; off < 256; off <<= 1) {
    int t = (threadIdx.x >= (unsigned)off) ? sdata[threadIdx.x - off] : 0;
    __syncthreads();
    sdata[threadIdx.x] += t;
    __syncthreads();
  }
  if (threadIdx.x < nb) bsum[threadIdx.x] = sdata[threadIdx.x] - v;
}

__global__ void k_scan3(const int* __restrict__ cnt, const int* __restrict__ bsum,
                        int* __restrict__ rowptr, int* __restrict__ cur, int n, int nnz) {
  __shared__ int sdata[256];
  int base = blockIdx.x * SCAN_CHUNK;
  int loc[8];
  int s = 0;
#pragma unroll
  for (int k = 0; k < 8; ++k) {
    int i = base + threadIdx.x * 8 + k;
    loc[k] = (i < n) ? cnt[i] : 0;
    s += loc[k];
  }
  sdata[threadIdx.x] = s;
  __syncthreads();
  for (int off = 1; off < 256; off <<= 1) {
    int t = (threadIdx.x >= (unsigned)off) ? sdata[threadIdx.x - off] : 0;
    __syncthreads();
    sdata[threadIdx.x] += t;
    __syncthreads();
  }
  int pre = bsum[blockIdx.x] + sdata[threadIdx.x] - s;
#pragma unroll
  for (int k = 0; k < 8; ++k) {
    int i = base + threadIdx.x * 8 + k;
    if (i < n) { rowptr[i] = pre; cur[i] = pre; pre += loc[k]; }
  }
  if (blockIdx.x == 0 && threadIdx.x == 0) rowptr[n] = nnz;
}

__global__ void k_scatter(const int* __restrict__ rows, const int* __restrict__ cols,
                          const float* __restrict__ vals, int* __restrict__ cur,
                          int2* __restrict__ cv, int nnz) {
  int idx = blockIdx.x * blockDim.x + threadIdx.x;
  for (; idx < nnz; idx += gridDim.x * blockDim.x) {
    int r = rows[idx];
    int p = atomicAdd(&cur[r], 1);
    cv[p] = make_int2(cols[idx], __float_as_int(vals[idx]));
  }
}

// ================= fused CSR SpMM kernels =================
// A-type: wave per row. r<NU: embNext=tanh(acc@Wi.T); r>=NU: embNext=acc, outF+=acc
__global__ void k_spmm_fusedA(const int* __restrict__ rowptr, const int2* __restrict__ cv,
                              const float* __restrict__ X, const float* __restrict__ W,
                              float* __restrict__ embNext, float* __restrict__ outF) {
  __shared__ float Wt[64 * 65];
  for (int idx = threadIdx.x; idx < 64 * 64; idx += blockDim.x)
    Wt[(idx & 63) * 65 + (idx >> 6)] = W[idx];
  __syncthreads();
  int lane = threadIdx.x & 63;
  int wid = (blockIdx.x * blockDim.x + threadIdx.x) >> 6;
  int nw = (gridDim.x * blockDim.x) >> 6;
  for (int r = wid; r < NTOT; r += nw) {
    float acc = row_gather(rowptr, cv, X, r, lane);
    if (r < NU) {
      embNext[(size_t)r * DD + lane] = tanhf(gemm64(acc, Wt, lane));
    } else {
      embNext[(size_t)r * DD + lane] = acc;
      outF[(size_t)r * DD + lane] += acc;
    }
  }
}

// Dual S-type: rows rr in [0,2NU). rr<NU: input xa -> ya (+logit wva@basea);
// else xb -> yb (+logit wvb@baseb). t = tanh(acc@W.T).
__global__ void k_spmm_fusedS2(const int* __restrict__ rowptr, const int2* __restrict__ cv,
                               const float* __restrict__ xa, const float* __restrict__ xb,
                               const float* __restrict__ W,
                               float* __restrict__ ya, float* __restrict__ yb,
                               const float* __restrict__ wva, const float* __restrict__ wvb,
                               const float* __restrict__ fkb, float* __restrict__ out_logits,
                               int basea, int baseb, int slot) {
  __shared__ float Wt[64 * 65];
  for (int idx = threadIdx.x; idx < 64 * 64; idx += blockDim.x)
    Wt[(idx & 63) * 65 + (idx >> 6)] = W[idx];
  __syncthreads();
  int lane = threadIdx.x & 63;
  int wid = (blockIdx.x * blockDim.x + threadIdx.x) >> 6;
  int nw = (gridDim.x * blockDim.x) >> 6;
  float b = fkb[0];
  for (int rr = wid; rr < 2 * NU; rr += nw) {
    bool first = rr < NU;
    int r = first ? rr : rr - NU;
    const float* xin = first ? xa : xb;
    float* xout = first ? ya : yb;
    const float* wvp = first ? wva : wvb;
    int base = first ? basea : baseb;
    float acc = row_gather(rowptr, cv, xin, r, lane);
    float t = tanhf(gemm64(acc, Wt, lane));
    xout[(size_t)r * DD + lane] = t;
    if (wvp) {
      float p = t * wvp[lane];
#pragma unroll
      for (int off = 32; off > 0; off >>= 1) p += __shfl_xor(p, off);
      if (lane == 0) out_logits[(size_t)(base + r) * 6 + slot] = p + b;
    }
  }
}

// ---------- fused column sums for both socials ----------
__global__ void k_colsum2(const float* __restrict__ x1, const float* __restrict__ x2,
                          float* __restrict__ c1, float* __restrict__ c2) {
  int lane = threadIdx.x & 63;
  int wid = (blockIdx.x * blockDim.x + threadIdx.x) >> 6;
  int nw = (gridDim.x * blockDim.x) >> 6;
  float a1 = 0.f, a2 = 0.f;
  for (int i = wid; i < NU; i += nw) {
    a1 += x1[(size_t)i * DD + lane];
    a2 += x2[(size_t)i * DD + lane];
  }
  atomicAdd(&c1[lane], a1);
  atomicAdd(&c2[lane], a2);
}

// ---------- w = fk_W @ (csum/NU) ----------
__global__ void k_wvec(const float* __restrict__ fkW, const float* __restrict__ c1r,
                       const float* __restrict__ c2r, float* __restrict__ w1,
                       float* __restrict__ w2) {
  int j = threadIdx.x;
  float a1 = 0.f, a2 = 0.f;
  for (int k = 0; k < 64; ++k) {
    float w = fkW[j * 64 + k];
    a1 += w * c1r[k];
    a2 += w * c2r[k];
  }
  w1[j] = a1 * (1.0f / NU);
  w2[j] = a2 * (1.0f / NU);
}

// ---------- true logits (identical across the 3 layers) ----------
__global__ void k_logits(const float* __restrict__ xa, const float* __restrict__ xb,
                         const float* __restrict__ w1, const float* __restrict__ w2,
                         const float* __restrict__ fkb, float* __restrict__ out_logits,
                         int slot_base, int nslots) {
  int lane = threadIdx.x & 63;
  int wid = (blockIdx.x * blockDim.x + threadIdx.x) >> 6;
  int nw = (gridDim.x * blockDim.x) >> 6;
  float b = fkb[0];
  for (int i = wid; i < 2 * NU; i += nw) {
    const float* xrow;
    float wv;
    if (i < NU) { xrow = xa + (size_t)i * DD;        wv = w1[lane]; }
    else        { xrow = xb + (size_t)(i - NU) * DD; wv = w2[lane]; }
    float p = xrow[lane] * wv;
#pragma unroll
    for (int off = 32; off > 0; off >>= 1) p += __shfl_xor(p, off);
    if (lane == 0) {
      float val = p + b;
      for (int s = 0; s < nslots; ++s) out_logits[(size_t)i * 6 + slot_base + s] = val;
    }
  }
}

// ---------- UC[i] = (0.5*(UC[i]+V[i])) @ Ws[:,64:].T (in-place) ----------
__global__ void k_comb_gemm(float* __restrict__ uc, const float* __restrict__ v,
                            const float* __restrict__ Ws) {
  __shared__ float Wt[64 * 65];
  for (int idx = threadIdx.x; idx < 64 * 64; idx += blockDim.x) {
    int j = idx >> 6, k = idx & 63;
    Wt[k * 65 + j] = Ws[j * 128 + 64 + k];
  }
  __syncthreads();
  int lane = threadIdx.x & 63;
  int wid = (blockIdx.x * blockDim.x + threadIdx.x) >> 6;
  int nw = (gridDim.x * blockDim.x) >> 6;
  for (int i = wid; i < NU; i += nw) {
    float c = 0.5f * (uc[(size_t)i * DD + lane] + v[(size_t)i * DD + lane]);
    uc[(size_t)i * DD + lane] = gemm64(c, Wt, lane);
  }
}

// ---------- users_raw = u_next @ Ws[:,:64].T + UC ; sum of squares ----------
__global__ void k_users(const float* __restrict__ u_next, const float* __restrict__ uc,
                        const float* __restrict__ Ws, float* __restrict__ users_raw,
                        float* __restrict__ sumsq) {
  __shared__ float Wt[64 * 65];
  for (int idx = threadIdx.x; idx < 64 * 64; idx += blockDim.x) {
    int j = idx >> 6, k = idx & 63;
    Wt[k * 65 + j] = Ws[j * 128 + k];
  }
  __syncthreads();
  int lane = threadIdx.x & 63;
  int wid = (blockIdx.x * blockDim.x + threadIdx.x) >> 6;
  int nw = (gridDim.x * blockDim.x) >> 6;
  float ss = 0.f;
  for (int i = wid; i < NU; i += nw) {
    float va = u_next[(size_t)i * DD + lane];
    float acc = uc[(size_t)i * DD + lane];
#pragma unroll
    for (int k = 0; k < 64; ++k) acc = fmaf(__shfl(va, k), Wt[k * 65 + lane], acc);
    users_raw[(size_t)i * DD + lane] = acc;
    ss += acc * acc;
  }
#pragma unroll
  for (int off = 32; off > 0; off >>= 1) ss += __shfl_xor(ss, off);
  if (lane == 0) atomicAdd(sumsq, ss);
}

__global__ void k_users_acc(const float* __restrict__ users_raw,
                            const float* __restrict__ sumsq, float* __restrict__ out_final) {
  float scale = 1.0f / sqrtf(*sumsq);
  int idx = blockIdx.x * blockDim.x + threadIdx.x;
  for (; idx < NU * DD; idx += gridDim.x * blockDim.x)
    out_final[idx] += users_raw[idx] * scale;
}

__global__ void k_scale(float* __restrict__ out_final) {
  int idx = blockIdx.x * blockDim.x + threadIdx.x;
  const int tot = NTOT * DD;
  for (; idx < tot; idx += gridDim.x * blockDim.x) out_final[idx] *= 0.25f;
}

extern "C" void kernel_launch(void* const* d_in, const int* in_sizes, int n_in,
                              void* d_out, int out_size, void* d_ws, size_t ws_size,
                              hipStream_t stream) {
  const float* u1      = (const float*)d_in[0];
  const float* u2      = (const float*)d_in[1];
  const float* item    = (const float*)d_in[2];
  const float* Wi      = (const float*)d_in[3];
  const float* Wc      = (const float*)d_in[4];
  const float* Ws      = (const float*)d_in[5];
  const float* fk_W    = (const float*)d_in[6];
  const float* fk_b    = (const float*)d_in[7];
  const float* A_vals  = (const float*)d_in[8];
  const float* A2_vals = (const float*)d_in[9];
  const float* S_vals  = (const float*)d_in[10];
  const int*   A_rows  = (const int*)d_in[11];
  const int*   A_cols  = (const int*)d_in[12];
  const int*   A2_rows = (const int*)d_in[13];
  const int*   A2_cols = (const int*)d_in[14];
  const int*   S_rows  = (const int*)d_in[15];
  const int*   S_cols  = (const int*)d_in[16];
  const int*   sh1     = (const int*)d_in[17];
  const int*   sh2     = (const int*)d_in[18];

  // ---- base workspace: 57,400,515 floats = 229.6 MB (proven-safe) ----
  float* ws   = (float*)d_ws;
  float* embA = ws;                              // 16,000,000 @ 0
  float* embB = embA + (size_t)NTOT * DD;        // 16,000,000 @ 16,000,000
  float* UC   = embB + (size_t)NTOT * DD;        // 6,400,000  @ 32,000,000
  float* n1   = UC + (size_t)NU * DD;            // 6,400,000  @ 38,400,000
  float* n2   = n1 + (size_t)NU * DD;            // 6,400,000  @ 44,800,000
  int2*  cvA  = (int2*)(n2 + (size_t)NU * DD);   // 2,000,000 int2 @ 51,200,000
  int2*  cvS  = cvA + NNZ_A;                     // 800,000 int2   @ 55,200,000
  int*   ptrA = (int*)(cvS + NNZ_S);             // 250,001 @ 56,800,000
  int*   ptrS = ptrA + (NTOT + 1);               // 100,001
  int*   cur  = ptrS + (NU + 1);                 // 250,000
  int*   bsum = cur + NTOT;                      // 256
  float* c1r  = (float*)(bsum + 256);            // 64
  float* c2r  = c1r + 64;
  float* w1   = c2r + 64;
  float* w2   = w1 + 64;
  float* sumsq = w2 + 64;                        // 1 -> end 57,400,515

  // optional persistent A2 CSR (gated on actual ws_size; deterministic)
  bool persist = ws_size >= 246602100ULL;
  int2* cvA2  = (int2*)(ws + 57400516);          // 8B-aligned (even float idx)
  int*  ptrA2 = (int*)(cvA2 + NNZ_A);

  float* out        = (float*)d_out;
  float* out_logits = out + (size_t)NTOT * DD;

  auto build = [&](const int* rows, const int* cols, const float* vals,
                   int n, int nnz, int* ptr, int2* cv) {
    int nb = (n + SCAN_CHUNK - 1) / SCAN_CHUNK;
    hipMemsetAsync(cur, 0, (size_t)n * sizeof(int), stream);
    k_hist<<<2048, 256, 0, stream>>>(rows, cur, nnz);
    k_scan1<<<nb, 256, 0, stream>>>(cur, bsum, n);
    k_scan2<<<1, 256, 0, stream>>>(bsum, nb);
    k_scan3<<<nb, 256, 0, stream>>>(cur, bsum, ptr, cur, n, nnz);
    k_scatter<<<2048, 256, 0, stream>>>(rows, cols, vals, cur, cv, nnz);
  };

  // ---------- CSR builds ----------
  build(S_rows, S_cols, S_vals, NU, NNZ_S, ptrS, cvS);
  build(A_rows, A_cols, A_vals, NTOT, NNZ_A, ptrA, cvA);
  if (persist) build(A2_rows, A2_cols, A2_vals, NTOT, NNZ_A, ptrA2, cvA2);

  // ---------- init ----------
  hipMemsetAsync(c1r, 0, 128 * sizeof(float), stream);
  k_init<<<2048, 256, 0, stream>>>(u1, u2, item, embA, out);
  k_gather<<<1024, 256, 0, stream>>>(u1, u2, sh1, sh2, n1, n2);

  // ---------- loop-invariant socials (dual): u1_soc -> UC, u2_soc -> embB ----------
  k_spmm_fusedS2<<<4096, 256, 0, stream>>>(ptrS, cvS, u1, u2, Wc, UC, embB,
                                           nullptr, nullptr, fk_b, out_logits, 0, 0, 0);
  k_colsum2<<<256, 256, 0, stream>>>(UC, embB, c1r, c2r);
  k_wvec<<<1, 64, 0, stream>>>(fk_W, c1r, c2r, w1, w2);
  // sc1 = u2_soc.w1 rows[0,NU); sc2 = u1_soc.w2 rows[NU,2NU); slots 0..2
  k_logits<<<1024, 256, 0, stream>>>(embB, UC, w1, w2, fk_b, out_logits, 0, 3);
  // UC := (0.5*(u1_soc+u2_soc)) @ Ws[:,64:].T  (loop-invariant half of k_users)
  k_comb_gemm<<<1024, 256, 0, stream>>>(UC, embB, Ws);

  // ---------- layer loop (3-buffer neg rotation, zero copies) ----------
  float* embCur = embA;
  float* embNext = embB;
  for (int l = 0; l < 3; ++l) {
    const int* pA; const int2* cA;
    if (l == 0)      { pA = ptrA;  cA = cvA;  }
    else if (persist){ pA = ptrA2; cA = cvA2; }
    else             { pA = ptrA;  cA = cvA;  }

    float* uraw;
    if (l == 1) {
      // negs live in embA regions (written at l=0); read them BEFORE fusedA overwrites
      k_spmm_fusedS2<<<4096, 256, 0, stream>>>(ptrS, cvS,
          embA, embA + (size_t)NU * DD, Wc, n1, n2,
          w2, w1, fk_b, out_logits, NU, 0, 3 + l);
      k_spmm_fusedA<<<4096, 256, 0, stream>>>(pA, cA, embCur, Wi, embNext, out);
      uraw = embCur;  // embB free after fusedA consumed it
    } else {
      k_spmm_fusedA<<<4096, 256, 0, stream>>>(pA, cA, embCur, Wi, embNext, out);
      if (l == 0 && !persist)
        build(A2_rows, A2_cols, A2_vals, NTOT, NNZ_A, ptrA, cvA);  // reuse A's buffers
      // negs n1,n2 -> dead embCur regions
      k_spmm_fusedS2<<<4096, 256, 0, stream>>>(ptrS, cvS,
          n1, n2, Wc, embCur, embCur + (size_t)NU * DD,
          w2, w1, fk_b, out_logits, NU, 0, 3 + l);
      uraw = n1;      // free after dual consumed it
    }

    hipMemsetAsync(sumsq, 0, sizeof(float), stream);
    k_users<<<1024, 256, 0, stream>>>(embNext, UC, Ws, uraw, sumsq);
    k_users_acc<<<2048, 256, 0, stream>>>(uraw, sumsq, out);

    { float* t = embCur; embCur = embNext; embNext = t; }
  }

  k_scale<<<2048, 256, 0, stream>>>(out);
}

// Round 5
// 2225.340 us; speedup vs baseline: 2.2503x; 1.2115x over previous
//
#include <hip/hip_runtime.h>

#define NU 100000
#define NI 150000
#define NTOT 250000
#define DD 64
#define NNZ_A 2000000
#define NNZ_S 800000
#define SCAN_CHUNK 2048  // 256 threads x 8

// ================= shared device helpers =================
// CSR row gather: acc[lane] = sum_e vals[e] * X[cols[e]*64 + lane]
// 8-way batched loads (MLP); col/val broadcast via readlane (wave-uniform ks,
// SGPR result -> scalar-base addressing, no ds_bpermute on the DS pipe).
__device__ __forceinline__ float row_gather(const int* __restrict__ rowptr,
                                            const int2* __restrict__ cv,
                                            const float* __restrict__ X,
                                            int r, int lane) {
  int start = rowptr[r], end = rowptr[r + 1];
  float acc = 0.f;
  for (int p0 = start; p0 < end; p0 += 64) {
    int n = min(64, end - p0);
    int2 e = cv[p0 + (lane < n ? lane : 0)];
    for (int k = 0; k < n; k += 8) {
      float x[8], vv[8];
#pragma unroll
      for (int u = 0; u < 8; ++u) {
        int kk = k + u;
        int ks = min(kk, n - 1);  // wave-uniform clamp
        int c = (int)__builtin_amdgcn_readlane((unsigned)e.x, (unsigned)ks);
        unsigned vb = __builtin_amdgcn_readlane((unsigned)e.y, (unsigned)ks);
        vv[u] = (kk < n) ? __uint_as_float(vb) : 0.f;  // pad v=0
        x[u] = X[(size_t)c * DD + lane];               // 8 loads in flight
      }
#pragma unroll
      for (int u = 0; u < 8; ++u) acc = fmaf(vv[u], x[u], acc);
    }
  }
  return acc;
}

// out[lane] = sum_k acc_bcast[k] * w[k]; w[] is the lane's OWN row of W in
// VGPRs -> zero DS-pipe ops (readlane with literal k + fma only).
__device__ __forceinline__ float gemm64_reg(float acc, const float* __restrict__ w) {
  float o = 0.f;
#pragma unroll
  for (int k = 0; k < 64; ++k) {
    float a = __uint_as_float(__builtin_amdgcn_readlane(__float_as_uint(acc), (unsigned)k));
    o = fmaf(a, w[k], o);
  }
  return o;
}

// load lane's row of staged W (Wl[j*65+k], pad 65 -> conflict-free) into regs
__device__ __forceinline__ void load_wreg(const float* __restrict__ Wl, int lane,
                                          float* __restrict__ w) {
#pragma unroll
  for (int k = 0; k < 64; ++k) w[k] = Wl[lane * 65 + k];
}

// ---------- init: all_emb = [(u1+u2)/2 ; item_emb]; out_final = all_emb ----------
__global__ void k_init(const float* __restrict__ u1, const float* __restrict__ u2,
                       const float* __restrict__ item, float* __restrict__ all_emb,
                       float* __restrict__ out_final) {
  int idx = blockIdx.x * blockDim.x + threadIdx.x;
  const int tot = NTOT * DD;
  const int nu = NU * DD;
  for (; idx < tot; idx += gridDim.x * blockDim.x) {
    float v;
    if (idx < nu) v = 0.5f * (u1[idx] + u2[idx]);
    else          v = item[idx - nu];
    all_emb[idx] = v;
    out_final[idx] = v;
  }
}

// ---------- gather negatives ----------
__global__ void k_gather(const float* __restrict__ u1, const float* __restrict__ u2,
                         const int* __restrict__ s1, const int* __restrict__ s2,
                         float* __restrict__ u1n, float* __restrict__ u2n) {
  int idx = blockIdx.x * blockDim.x + threadIdx.x;
  const int tot = NU * DD;
  for (; idx < tot; idx += gridDim.x * blockDim.x) {
    int i = idx >> 6, j = idx & 63;
    u1n[idx] = u1[s1[i] * DD + j];
    u2n[idx] = u2[s2[i] * DD + j];
  }
}

// ================= CSR build (counting sort) =================
__global__ void k_hist(const int* __restrict__ rows, int* __restrict__ cnt, int nnz) {
  int idx = blockIdx.x * blockDim.x + threadIdx.x;
  for (; idx < nnz; idx += gridDim.x * blockDim.x)
    atomicAdd(&cnt[rows[idx]], 1);
}

__global__ void k_scan1(const int* __restrict__ cnt, int* __restrict__ bsum, int n) {
  __shared__ int sdata[256];
  int base = blockIdx.x * SCAN_CHUNK;
  int s = 0;
#pragma unroll
  for (int k = 0; k < 8; ++k) {
    int i = base + threadIdx.x * 8 + k;
    s += (i < n) ? cnt[i] : 0;
  }
  sdata[threadIdx.x] = s;
  __syncthreads();
  for (int off = 128; off > 0; off >>= 1) {
    if (threadIdx.x < off) sdata[threadIdx.x] += sdata[threadIdx.x + off];
    __syncthreads();
  }
  if (threadIdx.x == 0) bsum[blockIdx.x] = sdata[0];
}

__global__ void k_scan2(int* bsum, int nb) {
  __shared__ int sdata[256];
  int v = (threadIdx.x < nb) ? bsum[threadIdx.x] : 0;
  sdata[threadIdx.x] = v;
  __syncthreads();
  for (int off = 1; off < 256; off <<= 1) {
    int t = (threadIdx.x >= (unsigned)off) ? sdata[threadIdx.x - off] : 0;
    __syncthreads();
    sdata[threadIdx.x] += t;
    __syncthreads();
  }
  if (threadIdx.x < nb) bsum[threadIdx.x] = sdata[threadIdx.x] - v;
}

__global__ void k_scan3(const int* __restrict__ cnt, const int* __restrict__ bsum,
                        int* __restrict__ rowptr, int* __restrict__ cur, int n, int nnz) {
  __shared__ int sdata[256];
  int base = blockIdx.x * SCAN_CHUNK;
  int loc[8];
  int s = 0;
#pragma unroll
  for (int k = 0; k < 8; ++k) {
    int i = base + threadIdx.x * 8 + k;
    loc[k] = (i < n) ? cnt[i] : 0;
    s += loc[k];
  }
  sdata[threadIdx.x] = s;
  __syncthreads();
  for (int off = 1; off < 256; off <<= 1) {
    int t = (threadIdx.x >= (unsigned)off) ? sdata[threadIdx.x - off] : 0;
    __syncthreads();
    sdata[threadIdx.x] += t;
    __syncthreads();
  }
  int pre = bsum[blockIdx.x] + sdata[threadIdx.x] - s;
#pragma unroll
  for (int k = 0; k < 8; ++k) {
    int i = base + threadIdx.x * 8 + k;
    if (i < n) { rowptr[i] = pre; cur[i] = pre; pre += loc[k]; }
  }
  if (blockIdx.x == 0 && threadIdx.x == 0) rowptr[n] = nnz;
}

__global__ void k_scatter(const int* __restrict__ rows, const int* __restrict__ cols,
                          const float* __restrict__ vals, int* __restrict__ cur,
                          int2* __restrict__ cv, int nnz) {
  int idx = blockIdx.x * blockDim.x + threadIdx.x;
  for (; idx < nnz; idx += gridDim.x * blockDim.x) {
    int r = rows[idx];
    int p = atomicAdd(&cur[r], 1);
    cv[p] = make_int2(cols[idx], __float_as_int(vals[idx]));
  }
}

// ================= fused CSR SpMM kernels =================
// A-type: wave per row. r<NU: embNext=tanh(acc@Wi.T); r>=NU: embNext=acc, outF+=acc
__global__ void k_spmm_fusedA(const int* __restrict__ rowptr, const int2* __restrict__ cv,
                              const float* __restrict__ X, const float* __restrict__ W,
                              float* __restrict__ embNext, float* __restrict__ outF) {
  __shared__ float Wl[64 * 65];  // Wl[j*65+k] = W[j][k]
  for (int idx = threadIdx.x; idx < 64 * 64; idx += blockDim.x)
    Wl[(idx >> 6) * 65 + (idx & 63)] = W[idx];
  __syncthreads();
  int lane = threadIdx.x & 63;
  float w[64];
  load_wreg(Wl, lane, w);
  int wid = (blockIdx.x * blockDim.x + threadIdx.x) >> 6;
  int nw = (gridDim.x * blockDim.x) >> 6;
  for (int r = wid; r < NTOT; r += nw) {
    float acc = row_gather(rowptr, cv, X, r, lane);
    if (r < NU) {
      embNext[(size_t)r * DD + lane] = tanhf(gemm64_reg(acc, w));
    } else {
      embNext[(size_t)r * DD + lane] = acc;
      outF[(size_t)r * DD + lane] += acc;
    }
  }
}

// Dual S-type: rows rr in [0,2NU). rr<NU: xa -> ya (+logit wva@basea);
// else xb -> yb (+logit wvb@baseb). t = tanh(acc@W.T).
__global__ void k_spmm_fusedS2(const int* __restrict__ rowptr, const int2* __restrict__ cv,
                               const float* __restrict__ xa, const float* __restrict__ xb,
                               const float* __restrict__ W,
                               float* __restrict__ ya, float* __restrict__ yb,
                               const float* __restrict__ wva, const float* __restrict__ wvb,
                               const float* __restrict__ fkb, float* __restrict__ out_logits,
                               int basea, int baseb, int slot) {
  __shared__ float Wl[64 * 65];
  for (int idx = threadIdx.x; idx < 64 * 64; idx += blockDim.x)
    Wl[(idx >> 6) * 65 + (idx & 63)] = W[idx];
  __syncthreads();
  int lane = threadIdx.x & 63;
  float w[64];
  load_wreg(Wl, lane, w);
  int wid = (blockIdx.x * blockDim.x + threadIdx.x) >> 6;
  int nw = (gridDim.x * blockDim.x) >> 6;
  float b = fkb[0];
  for (int rr = wid; rr < 2 * NU; rr += nw) {
    bool first = rr < NU;
    int r = first ? rr : rr - NU;
    const float* xin = first ? xa : xb;
    float* xout = first ? ya : yb;
    const float* wvp = first ? wva : wvb;
    int base = first ? basea : baseb;
    float acc = row_gather(rowptr, cv, xin, r, lane);
    float t = tanhf(gemm64_reg(acc, w));
    xout[(size_t)r * DD + lane] = t;
    if (wvp) {
      float p = t * wvp[lane];
#pragma unroll
      for (int off = 32; off > 0; off >>= 1) p += __shfl_xor(p, off);
      if (lane == 0) out_logits[(size_t)(base + r) * 6 + slot] = p + b;
    }
  }
}

// ---------- fused column sums for both socials ----------
__global__ void k_colsum2(const float* __restrict__ x1, const float* __restrict__ x2,
                          float* __restrict__ c1, float* __restrict__ c2) {
  int lane = threadIdx.x & 63;
  int wid = (blockIdx.x * blockDim.x + threadIdx.x) >> 6;
  int nw = (gridDim.x * blockDim.x) >> 6;
  float a1 = 0.f, a2 = 0.f;
  for (int i = wid; i < NU; i += nw) {
    a1 += x1[(size_t)i * DD + lane];
    a2 += x2[(size_t)i * DD + lane];
  }
  atomicAdd(&c1[lane], a1);
  atomicAdd(&c2[lane], a2);
}

// ---------- w = fk_W @ (csum/NU) ----------
__global__ void k_wvec(const float* __restrict__ fkW, const float* __restrict__ c1r,
                       const float* __restrict__ c2r, float* __restrict__ w1,
                       float* __restrict__ w2) {
  int j = threadIdx.x;
  float a1 = 0.f, a2 = 0.f;
  for (int k = 0; k < 64; ++k) {
    float w = fkW[j * 64 + k];
    a1 += w * c1r[k];
    a2 += w * c2r[k];
  }
  w1[j] = a1 * (1.0f / NU);
  w2[j] = a2 * (1.0f / NU);
}

// ---------- true logits (identical across the 3 layers) ----------
__global__ void k_logits(const float* __restrict__ xa, const float* __restrict__ xb,
                         const float* __restrict__ w1, const float* __restrict__ w2,
                         const float* __restrict__ fkb, float* __restrict__ out_logits,
                         int slot_base, int nslots) {
  int lane = threadIdx.x & 63;
  int wid = (blockIdx.x * blockDim.x + threadIdx.x) >> 6;
  int nw = (gridDim.x * blockDim.x) >> 6;
  float b = fkb[0];
  for (int i = wid; i < 2 * NU; i += nw) {
    const float* xrow;
    float wv;
    if (i < NU) { xrow = xa + (size_t)i * DD;        wv = w1[lane]; }
    else        { xrow = xb + (size_t)(i - NU) * DD; wv = w2[lane]; }
    float p = xrow[lane] * wv;
#pragma unroll
    for (int off = 32; off > 0; off >>= 1) p += __shfl_xor(p, off);
    if (lane == 0) {
      float val = p + b;
      for (int s = 0; s < nslots; ++s) out_logits[(size_t)i * 6 + slot_base + s] = val;
    }
  }
}

// ---------- UC[i] = (0.5*(UC[i]+V[i])) @ Ws[:,64:].T (in-place) ----------
__global__ void k_comb_gemm(float* __restrict__ uc, const float* __restrict__ v,
                            const float* __restrict__ Ws) {
  __shared__ float Wl[64 * 65];
  for (int idx = threadIdx.x; idx < 64 * 64; idx += blockDim.x) {
    int j = idx >> 6, k = idx & 63;
    Wl[j * 65 + k] = Ws[j * 128 + 64 + k];
  }
  __syncthreads();
  int lane = threadIdx.x & 63;
  float w[64];
  load_wreg(Wl, lane, w);
  int wid = (blockIdx.x * blockDim.x + threadIdx.x) >> 6;
  int nw = (gridDim.x * blockDim.x) >> 6;
  for (int i = wid; i < NU; i += nw) {
    float c = 0.5f * (uc[(size_t)i * DD + lane] + v[(size_t)i * DD + lane]);
    uc[(size_t)i * DD + lane] = gemm64_reg(c, w);
  }
}

// ---------- users_raw = u_next @ Ws[:,:64].T + UC ; sum of squares ----------
__global__ void k_users(const float* __restrict__ u_next, const float* __restrict__ uc,
                        const float* __restrict__ Ws, float* __restrict__ users_raw,
                        float* __restrict__ sumsq) {
  __shared__ float Wl[64 * 65];
  for (int idx = threadIdx.x; idx < 64 * 64; idx += blockDim.x) {
    int j = idx >> 6, k = idx & 63;
    Wl[j * 65 + k] = Ws[j * 128 + k];
  }
  __syncthreads();
  int lane = threadIdx.x & 63;
  float w[64];
  load_wreg(Wl, lane, w);
  int wid = (blockIdx.x * blockDim.x + threadIdx.x) >> 6;
  int nw = (gridDim.x * blockDim.x) >> 6;
  float ss = 0.f;
  for (int i = wid; i < NU; i += nw) {
    float va = u_next[(size_t)i * DD + lane];
    float acc = uc[(size_t)i * DD + lane] + gemm64_reg(va, w);
    users_raw[(size_t)i * DD + lane] = acc;
    ss += acc * acc;
  }
#pragma unroll
  for (int off = 32; off > 0; off >>= 1) ss += __shfl_xor(ss, off);
  if (lane == 0) atomicAdd(sumsq, ss);
}

__global__ void k_users_acc(const float* __restrict__ users_raw,
                            const float* __restrict__ sumsq, float* __restrict__ out_final) {
  float scale = 1.0f / sqrtf(*sumsq);
  int idx = blockIdx.x * blockDim.x + threadIdx.x;
  for (; idx < NU * DD; idx += gridDim.x * blockDim.x)
    out_final[idx] += users_raw[idx] * scale;
}

__global__ void k_scale(float* __restrict__ out_final) {
  int idx = blockIdx.x * blockDim.x + threadIdx.x;
  const int tot = NTOT * DD;
  for (; idx < tot; idx += gridDim.x * blockDim.x) out_final[idx] *= 0.25f;
}

extern "C" void kernel_launch(void* const* d_in, const int* in_sizes, int n_in,
                              void* d_out, int out_size, void* d_ws, size_t ws_size,
                              hipStream_t stream) {
  const float* u1      = (const float*)d_in[0];
  const float* u2      = (const float*)d_in[1];
  const float* item    = (const float*)d_in[2];
  const float* Wi      = (const float*)d_in[3];
  const float* Wc      = (const float*)d_in[4];
  const float* Ws      = (const float*)d_in[5];
  const float* fk_W    = (const float*)d_in[6];
  const float* fk_b    = (const float*)d_in[7];
  const float* A_vals  = (const float*)d_in[8];
  const float* A2_vals = (const float*)d_in[9];
  const float* S_vals  = (const float*)d_in[10];
  const int*   A_rows  = (const int*)d_in[11];
  const int*   A_cols  = (const int*)d_in[12];
  const int*   A2_rows = (const int*)d_in[13];
  const int*   A2_cols = (const int*)d_in[14];
  const int*   S_rows  = (const int*)d_in[15];
  const int*   S_cols  = (const int*)d_in[16];
  const int*   sh1     = (const int*)d_in[17];
  const int*   sh2     = (const int*)d_in[18];

  // ---- base workspace: 57,400,515 floats = 229.6 MB (proven-safe) ----
  float* ws   = (float*)d_ws;
  float* embA = ws;                              // 16,000,000 @ 0
  float* embB = embA + (size_t)NTOT * DD;        // 16,000,000 @ 16,000,000
  float* UC   = embB + (size_t)NTOT * DD;        // 6,400,000  @ 32,000,000
  float* n1   = UC + (size_t)NU * DD;            // 6,400,000  @ 38,400,000
  float* n2   = n1 + (size_t)NU * DD;            // 6,400,000  @ 44,800,000
  int2*  cvA  = (int2*)(n2 + (size_t)NU * DD);   // 2,000,000 int2 @ 51,200,000
  int2*  cvS  = cvA + NNZ_A;                     // 800,000 int2   @ 55,200,000
  int*   ptrA = (int*)(cvS + NNZ_S);             // 250,001 @ 56,800,000
  int*   ptrS = ptrA + (NTOT + 1);               // 100,001
  int*   cur  = ptrS + (NU + 1);                 // 250,000
  int*   bsum = cur + NTOT;                      // 256
  float* c1r  = (float*)(bsum + 256);            // 64
  float* c2r  = c1r + 64;
  float* w1   = c2r + 64;
  float* w2   = w1 + 64;
  float* sumsq = w2 + 64;                        // 1 -> end 57,400,515

  // optional persistent A2 CSR (gated on actual ws_size; deterministic)
  bool persist = ws_size >= 246602100ULL;
  int2* cvA2  = (int2*)(ws + 57400516);          // 8B-aligned (even float idx)
  int*  ptrA2 = (int*)(cvA2 + NNZ_A);

  float* out        = (float*)d_out;
  float* out_logits = out + (size_t)NTOT * DD;

  auto build = [&](const int* rows, const int* cols, const float* vals,
                   int n, int nnz, int* ptr, int2* cv) {
    int nb = (n + SCAN_CHUNK - 1) / SCAN_CHUNK;
    hipMemsetAsync(cur, 0, (size_t)n * sizeof(int), stream);
    k_hist<<<2048, 256, 0, stream>>>(rows, cur, nnz);
    k_scan1<<<nb, 256, 0, stream>>>(cur, bsum, n);
    k_scan2<<<1, 256, 0, stream>>>(bsum, nb);
    k_scan3<<<nb, 256, 0, stream>>>(cur, bsum, ptr, cur, n, nnz);
    k_scatter<<<2048, 256, 0, stream>>>(rows, cols, vals, cur, cv, nnz);
  };

  // ---------- CSR builds ----------
  build(S_rows, S_cols, S_vals, NU, NNZ_S, ptrS, cvS);
  build(A_rows, A_cols, A_vals, NTOT, NNZ_A, ptrA, cvA);
  if (persist) build(A2_rows, A2_cols, A2_vals, NTOT, NNZ_A, ptrA2, cvA2);

  // ---------- init ----------
  hipMemsetAsync(c1r, 0, 128 * sizeof(float), stream);
  k_init<<<2048, 256, 0, stream>>>(u1, u2, item, embA, out);
  k_gather<<<1024, 256, 0, stream>>>(u1, u2, sh1, sh2, n1, n2);

  // ---------- loop-invariant socials (dual): u1_soc -> UC, u2_soc -> embB ----------
  k_spmm_fusedS2<<<4096, 256, 0, stream>>>(ptrS, cvS, u1, u2, Wc, UC, embB,
                                           nullptr, nullptr, fk_b, out_logits, 0, 0, 0);
  k_colsum2<<<256, 256, 0, stream>>>(UC, embB, c1r, c2r);
  k_wvec<<<1, 64, 0, stream>>>(fk_W, c1r, c2r, w1, w2);
  // sc1 = u2_soc.w1 rows[0,NU); sc2 = u1_soc.w2 rows[NU,2NU); slots 0..2
  k_logits<<<1024, 256, 0, stream>>>(embB, UC, w1, w2, fk_b, out_logits, 0, 3);
  // UC := (0.5*(u1_soc+u2_soc)) @ Ws[:,64:].T  (loop-invariant half of k_users)
  k_comb_gemm<<<1024, 256, 0, stream>>>(UC, embB, Ws);

  // ---------- layer loop (3-buffer neg rotation, zero copies) ----------
  float* embCur = embA;
  float* embNext = embB;
  for (int l = 0; l < 3; ++l) {
    const int* pA; const int2* cA;
    if (l == 0)      { pA = ptrA;  cA = cvA;  }
    else if (persist){ pA = ptrA2; cA = cvA2; }
    else             { pA = ptrA;  cA = cvA;  }

    float* uraw;
    if (l == 1) {
      // negs live in embA regions (written at l=0); read them BEFORE fusedA overwrites
      k_spmm_fusedS2<<<4096, 256, 0, stream>>>(ptrS, cvS,
          embA, embA + (size_t)NU * DD, Wc, n1, n2,
          w2, w1, fk_b, out_logits, NU, 0, 3 + l);
      k_spmm_fusedA<<<4096, 256, 0, stream>>>(pA, cA, embCur, Wi, embNext, out);
      uraw = embCur;  // embB free after fusedA consumed it
    } else {
      k_spmm_fusedA<<<4096, 256, 0, stream>>>(pA, cA, embCur, Wi, embNext, out);
      if (l == 0 && !persist)
        build(A2_rows, A2_cols, A2_vals, NTOT, NNZ_A, ptrA, cvA);  // reuse A's buffers
      // negs n1,n2 -> dead embCur regions
      k_spmm_fusedS2<<<4096, 256, 0, stream>>>(ptrS, cvS,
          n1, n2, Wc, embCur, embCur + (size_t)NU * DD,
          w2, w1, fk_b, out_logits, NU, 0, 3 + l);
      uraw = n1;      // free after dual consumed it
    }

    hipMemsetAsync(sumsq, 0, sizeof(float), stream);
    k_users<<<1024, 256, 0, stream>>>(embNext, UC, Ws, uraw, sumsq);
    k_users_acc<<<2048, 256, 0, stream>>>(uraw, sumsq, out);

    { float* t = embCur; embCur = embNext; embNext = t; }
  }

  k_scale<<<2048, 256, 0, stream>>>(out);
}

// Round 6
// 2033.926 us; speedup vs baseline: 2.4621x; 1.0941x over previous
//
#include <hip/hip_runtime.h>

#define NU 100000
#define NI 150000
#define NTOT 250000
#define DD 64
#define NNZ_A 2000000
#define NNZ_S 800000
#define SCAN_CHUNK 2048  // 256 threads x 8

// ================= shared device helpers =================
#define RDLANE_F(x, k) __uint_as_float(__builtin_amdgcn_readlane(__float_as_uint(x), (unsigned)(k)))
#define RDLANE_I(x, k) ((int)__builtin_amdgcn_readlane((unsigned)(x), (unsigned)(k)))

// load lane's row of staged W (Wl[j*65+k]) into regs and PIN to VGPRs
// (without the pin, the compiler re-reads LDS inside the fma loop: 64 ds_read/row)
__device__ __forceinline__ void load_wreg(const float* __restrict__ Wl, int lane,
                                          float* __restrict__ w) {
#pragma unroll
  for (int k = 0; k < 64; ++k) w[k] = Wl[lane * 65 + k];
#pragma unroll
  for (int k = 0; k < 64; ++k) asm("" : "+v"(w[k]));
}

__device__ __forceinline__ void gemm64x2(float aA, float aB, const float* __restrict__ w,
                                         float& oA, float& oB) {
  oA = 0.f; oB = 0.f;
#pragma unroll
  for (int k = 0; k < 64; ++k) {
    oA = fmaf(RDLANE_F(aA, k), w[k], oA);
    oB = fmaf(RDLANE_F(aB, k), w[k], oB);
  }
}

__device__ __forceinline__ void gemm64x4(float a1, float a2, float a3, float a4,
                                         const float* __restrict__ w,
                                         float& o1, float& o2, float& o3, float& o4) {
  o1 = 0.f; o2 = 0.f; o3 = 0.f; o4 = 0.f;
#pragma unroll
  for (int k = 0; k < 64; ++k) {
    float wk = w[k];
    o1 = fmaf(RDLANE_F(a1, k), wk, o1);
    o2 = fmaf(RDLANE_F(a2, k), wk, o2);
    o3 = fmaf(RDLANE_F(a3, k), wk, o3);
    o4 = fmaf(RDLANE_F(a4, k), wk, o4);
  }
}

// ---------- init: all_emb = [(u1+u2)/2 ; item_emb]; out_final = all_emb ----------
__global__ void k_init(const float* __restrict__ u1, const float* __restrict__ u2,
                       const float* __restrict__ item, float* __restrict__ all_emb,
                       float* __restrict__ out_final) {
  int idx = blockIdx.x * blockDim.x + threadIdx.x;
  const int tot = NTOT * DD;
  const int nu = NU * DD;
  for (; idx < tot; idx += gridDim.x * blockDim.x) {
    float v;
    if (idx < nu) v = 0.5f * (u1[idx] + u2[idx]);
    else          v = item[idx - nu];
    all_emb[idx] = v;
    out_final[idx] = v;
  }
}

// ================= CSR build (counting sort) =================
__global__ void k_hist(const int* __restrict__ rows, int* __restrict__ cnt, int nnz) {
  int idx = blockIdx.x * blockDim.x + threadIdx.x;
  for (; idx < nnz; idx += gridDim.x * blockDim.x)
    atomicAdd(&cnt[rows[idx]], 1);
}

__global__ void k_scan1(const int* __restrict__ cnt, int* __restrict__ bsum, int n) {
  __shared__ int sdata[256];
  int base = blockIdx.x * SCAN_CHUNK;
  int s = 0;
#pragma unroll
  for (int k = 0; k < 8; ++k) {
    int i = base + threadIdx.x * 8 + k;
    s += (i < n) ? cnt[i] : 0;
  }
  sdata[threadIdx.x] = s;
  __syncthreads();
  for (int off = 128; off > 0; off >>= 1) {
    if (threadIdx.x < off) sdata[threadIdx.x] += sdata[threadIdx.x + off];
    __syncthreads();
  }
  if (threadIdx.x == 0) bsum[blockIdx.x] = sdata[0];
}

__global__ void k_scan2(int* bsum, int nb) {
  __shared__ int sdata[256];
  int v = (threadIdx.x < nb) ? bsum[threadIdx.x] : 0;
  sdata[threadIdx.x] = v;
  __syncthreads();
  for (int off = 1; off < 256; off <<= 1) {
    int t = (threadIdx.x >= (unsigned)off) ? sdata[threadIdx.x - off] : 0;
    __syncthreads();
    sdata[threadIdx.x] += t;
    __syncthreads();
  }
  if (threadIdx.x < nb) bsum[threadIdx.x] = sdata[threadIdx.x] - v;
}

__global__ void k_scan3(const int* __restrict__ cnt, const int* __restrict__ bsum,
                        int* __restrict__ rowptr, int* __restrict__ cur, int n, int nnz) {
  __shared__ int sdata[256];
  int base = blockIdx.x * SCAN_CHUNK;
  int loc[8];
  int s = 0;
#pragma unroll
  for (int k = 0; k < 8; ++k) {
    int i = base + threadIdx.x * 8 + k;
    loc[k] = (i < n) ? cnt[i] : 0;
    s += loc[k];
  }
  sdata[threadIdx.x] = s;
  __syncthreads();
  for (int off = 1; off < 256; off <<= 1) {
    int t = (threadIdx.x >= (unsigned)off) ? sdata[threadIdx.x - off] : 0;
    __syncthreads();
    sdata[threadIdx.x] += t;
    __syncthreads();
  }
  int pre = bsum[blockIdx.x] + sdata[threadIdx.x] - s;
#pragma unroll
  for (int k = 0; k < 8; ++k) {
    int i = base + threadIdx.x * 8 + k;
    if (i < n) { rowptr[i] = pre; cur[i] = pre; pre += loc[k]; }
  }
  if (blockIdx.x == 0 && threadIdx.x == 0) rowptr[n] = nnz;
}

__global__ void k_scatter(const int* __restrict__ rows, const int* __restrict__ cols,
                          const float* __restrict__ vals, int* __restrict__ cur,
                          int2* __restrict__ cv, int nnz) {
  int idx = blockIdx.x * blockDim.x + threadIdx.x;
  for (; idx < nnz; idx += gridDim.x * blockDim.x) {
    int r = rows[idx];
    int p = atomicAdd(&cur[r], 1);
    cv[p] = make_int2(cols[idx], __float_as_int(vals[idx]));
  }
}

// cs1[p] = sh1[cv[p].x], cs2[p] = sh2[cv[p].x]  (fold neg-shuffle into cols)
__global__ void k_mapcols(const int2* __restrict__ cv, const int* __restrict__ s1,
                          const int* __restrict__ s2, int* __restrict__ cs1,
                          int* __restrict__ cs2, int nnz) {
  int idx = blockIdx.x * blockDim.x + threadIdx.x;
  for (; idx < nnz; idx += gridDim.x * blockDim.x) {
    int c = cv[idx].x;
    cs1[idx] = s1[c];
    cs2[idx] = s2[c];
  }
}

// ================= fused CSR SpMM kernels =================
// A-type, 2 rows per wave: 16 gather loads in flight, 2 interleaved gemm chains.
__global__ void k_spmm_fusedA2(const int* __restrict__ rowptr, const int2* __restrict__ cv,
                               const float* __restrict__ X, const float* __restrict__ W,
                               float* __restrict__ embNext, float* __restrict__ outF) {
  __shared__ float Wl[64 * 65];  // Wl[j*65+k] = W[j][k]
  for (int idx = threadIdx.x; idx < 64 * 64; idx += blockDim.x)
    Wl[(idx >> 6) * 65 + (idx & 63)] = W[idx];
  __syncthreads();
  int lane = threadIdx.x & 63;
  float w[64];
  load_wreg(Wl, lane, w);
  int wid = (blockIdx.x * blockDim.x + threadIdx.x) >> 6;
  int nw = (gridDim.x * blockDim.x) >> 6;
  for (int r = wid * 2; r < NTOT; r += nw * 2) {
    int sA = rowptr[r], m = rowptr[r + 1], eB = rowptr[r + 2];
    float accA = 0.f, accB = 0.f;
    for (int pA = sA, pB = m; pA < m || pB < eB; pA += 64, pB += 64) {
      int nA = (pA < m) ? min(64, m - pA) : 0;
      int nB = (pB < eB) ? min(64, eB - pB) : 0;
      int2 eAv = cv[(nA ? pA : 0) + (lane < nA ? lane : 0)];
      int2 eBv = cv[(nB ? pB : 0) + (lane < nB ? lane : 0)];
      int kmax = max(nA, nB);
      for (int k = 0; k < kmax; k += 8) {
        float xA[8], vA[8], xB[8], vB[8];
#pragma unroll
        for (int u = 0; u < 8; ++u) {
          int kk = k + u;
          int ksA = min(kk, max(nA - 1, 0));
          int ksB = min(kk, max(nB - 1, 0));
          int cA = RDLANE_I(eAv.x, ksA);
          int cB = RDLANE_I(eBv.x, ksB);
          vA[u] = (kk < nA) ? RDLANE_F(__int_as_float(eAv.y), ksA) : 0.f;
          vB[u] = (kk < nB) ? RDLANE_F(__int_as_float(eBv.y), ksB) : 0.f;
          xA[u] = X[(size_t)cA * DD + lane];
          xB[u] = X[(size_t)cB * DD + lane];
        }
#pragma unroll
        for (int u = 0; u < 8; ++u) {
          accA = fmaf(vA[u], xA[u], accA);
          accB = fmaf(vB[u], xB[u], accB);
        }
      }
    }
    if (r < NU) {  // NU even: pair never straddles
      float oA, oB;
      gemm64x2(accA, accB, w, oA, oB);
      embNext[(size_t)r * DD + lane] = tanhf(oA);
      embNext[(size_t)(r + 1) * DD + lane] = tanhf(oB);
    } else {
      embNext[(size_t)r * DD + lane] = accA;
      embNext[(size_t)(r + 1) * DD + lane] = accB;
      outF[(size_t)r * DD + lane] += accA;
      outF[(size_t)(r + 1) * DD + lane] += accB;
    }
  }
}

// Quad S-type: one row visit gathers 4 tables (u1, u2, u1∘sh1, u2∘sh2).
// y1=tanh(S·u1 Wc.T), y2=..., y3=neg1_0, y4=neg2_0. No logits (w not ready yet).
__global__ void k_spmm_quadS(const int* __restrict__ rowptr, const int2* __restrict__ cv,
                             const int* __restrict__ cs1, const int* __restrict__ cs2,
                             const float* __restrict__ u1, const float* __restrict__ u2,
                             const float* __restrict__ W,
                             float* __restrict__ y1, float* __restrict__ y2,
                             float* __restrict__ y3, float* __restrict__ y4) {
  __shared__ float Wl[64 * 65];
  for (int idx = threadIdx.x; idx < 64 * 64; idx += blockDim.x)
    Wl[(idx >> 6) * 65 + (idx & 63)] = W[idx];
  __syncthreads();
  int lane = threadIdx.x & 63;
  float w[64];
  load_wreg(Wl, lane, w);
  int wid = (blockIdx.x * blockDim.x + threadIdx.x) >> 6;
  int nw = (gridDim.x * blockDim.x) >> 6;
  for (int r = wid; r < NU; r += nw) {
    int start = rowptr[r], end = rowptr[r + 1];
    float a1 = 0.f, a2 = 0.f, a3 = 0.f, a4 = 0.f;
    for (int p0 = start; p0 < end; p0 += 64) {
      int n = min(64, end - p0);
      int idx = p0 + (lane < n ? lane : 0);
      int2 e = cv[idx];
      int m1 = cs1[idx];
      int m2 = cs2[idx];
      for (int k = 0; k < n; k += 4) {
        float x1[4], x2[4], x3[4], x4[4], vv[4];
#pragma unroll
        for (int u = 0; u < 4; ++u) {
          int kk = k + u;
          int ks = min(kk, n - 1);
          int c  = RDLANE_I(e.x, ks);
          int g1 = RDLANE_I(m1, ks);
          int g2 = RDLANE_I(m2, ks);
          vv[u] = (kk < n) ? RDLANE_F(__int_as_float(e.y), ks) : 0.f;
          x1[u] = u1[(size_t)c * DD + lane];
          x2[u] = u2[(size_t)c * DD + lane];
          x3[u] = u1[(size_t)g1 * DD + lane];
          x4[u] = u2[(size_t)g2 * DD + lane];
        }
#pragma unroll
        for (int u = 0; u < 4; ++u) {
          a1 = fmaf(vv[u], x1[u], a1);
          a2 = fmaf(vv[u], x2[u], a2);
          a3 = fmaf(vv[u], x3[u], a3);
          a4 = fmaf(vv[u], x4[u], a4);
        }
      }
    }
    float o1, o2, o3, o4;
    gemm64x4(a1, a2, a3, a4, w, o1, o2, o3, o4);
    y1[(size_t)r * DD + lane] = tanhf(o1);
    y2[(size_t)r * DD + lane] = tanhf(o2);
    y3[(size_t)r * DD + lane] = tanhf(o3);
    y4[(size_t)r * DD + lane] = tanhf(o4);
  }
}

// Dual S-type (neg recursion, layers 1-2): same edges, 2 tables; fused logits.
// ya=tanh(S·xa Wc.T) + logit wva @ rows [NU,2NU); yb likewise @ rows [0,NU).
__global__ void k_spmm_dualS(const int* __restrict__ rowptr, const int2* __restrict__ cv,
                             const float* __restrict__ xa, const float* __restrict__ xb,
                             const float* __restrict__ W,
                             float* __restrict__ ya, float* __restrict__ yb,
                             const float* __restrict__ wva, const float* __restrict__ wvb,
                             const float* __restrict__ fkb, float* __restrict__ out_logits,
                             int slot) {
  __shared__ float Wl[64 * 65];
  for (int idx = threadIdx.x; idx < 64 * 64; idx += blockDim.x)
    Wl[(idx >> 6) * 65 + (idx & 63)] = W[idx];
  __syncthreads();
  int lane = threadIdx.x & 63;
  float w[64];
  load_wreg(Wl, lane, w);
  int wid = (blockIdx.x * blockDim.x + threadIdx.x) >> 6;
  int nw = (gridDim.x * blockDim.x) >> 6;
  float b = fkb[0];
  float wa = wva[lane], wb = wvb[lane];
  for (int r = wid; r < NU; r += nw) {
    int start = rowptr[r], end = rowptr[r + 1];
    float accA = 0.f, accB = 0.f;
    for (int p0 = start; p0 < end; p0 += 64) {
      int n = min(64, end - p0);
      int2 e = cv[p0 + (lane < n ? lane : 0)];
      for (int k = 0; k < n; k += 8) {
        float xA[8], xB[8], vv[8];
#pragma unroll
        for (int u = 0; u < 8; ++u) {
          int kk = k + u;
          int ks = min(kk, n - 1);
          int c = RDLANE_I(e.x, ks);
          vv[u] = (kk < n) ? RDLANE_F(__int_as_float(e.y), ks) : 0.f;
          xA[u] = xa[(size_t)c * DD + lane];
          xB[u] = xb[(size_t)c * DD + lane];
        }
#pragma unroll
        for (int u = 0; u < 8; ++u) {
          accA = fmaf(vv[u], xA[u], accA);
          accB = fmaf(vv[u], xB[u], accB);
        }
      }
    }
    float oA, oB;
    gemm64x2(accA, accB, w, oA, oB);
    float ta = tanhf(oA), tb = tanhf(oB);
    ya[(size_t)r * DD + lane] = ta;
    yb[(size_t)r * DD + lane] = tb;
    float pa = ta * wa, pb = tb * wb;
#pragma unroll
    for (int off = 32; off > 0; off >>= 1) {
      pa += __shfl_xor(pa, off);
      pb += __shfl_xor(pb, off);
    }
    if (lane == 0) {
      out_logits[(size_t)(NU + r) * 6 + slot] = pa + b;
      out_logits[(size_t)r * 6 + slot] = pb + b;
    }
  }
}

// ---------- fused column sums for both socials ----------
__global__ void k_colsum2(const float* __restrict__ x1, const float* __restrict__ x2,
                          float* __restrict__ c1, float* __restrict__ c2) {
  int lane = threadIdx.x & 63;
  int wid = (blockIdx.x * blockDim.x + threadIdx.x) >> 6;
  int nw = (gridDim.x * blockDim.x) >> 6;
  float a1 = 0.f, a2 = 0.f;
  for (int i = wid; i < NU; i += nw) {
    a1 += x1[(size_t)i * DD + lane];
    a2 += x2[(size_t)i * DD + lane];
  }
  atomicAdd(&c1[lane], a1);
  atomicAdd(&c2[lane], a2);
}

// ---------- w = fk_W @ (csum/NU) ----------
__global__ void k_wvec(const float* __restrict__ fkW, const float* __restrict__ c1r,
                       const float* __restrict__ c2r, float* __restrict__ w1,
                       float* __restrict__ w2) {
  int j = threadIdx.x;
  float a1 = 0.f, a2 = 0.f;
  for (int k = 0; k < 64; ++k) {
    float w = fkW[j * 64 + k];
    a1 += w * c1r[k];
    a2 += w * c2r[k];
  }
  w1[j] = a1 * (1.0f / NU);
  w2[j] = a2 * (1.0f / NU);
}

// ---------- logits: true slots 0-2 (all layers) + false slot 3 (layer 0) ----------
__global__ void k_logits4(const float* __restrict__ u1s, const float* __restrict__ u2s,
                          const float* __restrict__ n1o, const float* __restrict__ n2o,
                          const float* __restrict__ w1, const float* __restrict__ w2,
                          const float* __restrict__ fkb, float* __restrict__ out_logits) {
  int lane = threadIdx.x & 63;
  int wid = (blockIdx.x * blockDim.x + threadIdx.x) >> 6;
  int nw = (gridDim.x * blockDim.x) >> 6;
  float b = fkb[0];
  for (int i = wid; i < 2 * NU; i += nw) {
    bool lo = i < NU;
    int r = lo ? i : i - NU;
    const float* xs = lo ? u2s : u1s;
    const float* xn = lo ? n2o : n1o;
    const float* wv = lo ? w1 : w2;
    float wvl = wv[lane];
    float ps = xs[(size_t)r * DD + lane] * wvl;
    float pn = xn[(size_t)r * DD + lane] * wvl;
#pragma unroll
    for (int off = 32; off > 0; off >>= 1) {
      ps += __shfl_xor(ps, off);
      pn += __shfl_xor(pn, off);
    }
    if (lane == 0) {
      float vs = ps + b;
      out_logits[(size_t)i * 6 + 0] = vs;
      out_logits[(size_t)i * 6 + 1] = vs;
      out_logits[(size_t)i * 6 + 2] = vs;
      out_logits[(size_t)i * 6 + 3] = pn + b;
    }
  }
}

// ---------- UC[i] = (0.5*(UC[i]+V[i])) @ Ws[:,64:].T (in-place) ----------
__global__ void k_comb_gemm(float* __restrict__ uc, const float* __restrict__ v,
                            const float* __restrict__ Ws) {
  __shared__ float Wl[64 * 65];
  for (int idx = threadIdx.x; idx < 64 * 64; idx += blockDim.x) {
    int j = idx >> 6, k = idx & 63;
    Wl[j * 65 + k] = Ws[j * 128 + 64 + k];
  }
  __syncthreads();
  int lane = threadIdx.x & 63;
  float w[64];
  load_wreg(Wl, lane, w);
  int wid = (blockIdx.x * blockDim.x + threadIdx.x) >> 6;
  int nw = (gridDim.x * blockDim.x) >> 6;
  for (int i = wid; i < NU; i += nw) {
    float c = 0.5f * (uc[(size_t)i * DD + lane] + v[(size_t)i * DD + lane]);
    float o = 0.f;
#pragma unroll
    for (int k = 0; k < 64; ++k) o = fmaf(RDLANE_F(c, k), w[k], o);
    uc[(size_t)i * DD + lane] = o;
  }
}

// ---------- users_raw = u_next @ Ws[:,:64].T + UC ; sum of squares ----------
__global__ void k_users(const float* __restrict__ u_next, const float* __restrict__ uc,
                        const float* __restrict__ Ws, float* __restrict__ users_raw,
                        float* __restrict__ sumsq) {
  __shared__ float Wl[64 * 65];
  for (int idx = threadIdx.x; idx < 64 * 64; idx += blockDim.x) {
    int j = idx >> 6, k = idx & 63;
    Wl[j * 65 + k] = Ws[j * 128 + k];
  }
  __syncthreads();
  int lane = threadIdx.x & 63;
  float w[64];
  load_wreg(Wl, lane, w);
  int wid = (blockIdx.x * blockDim.x + threadIdx.x) >> 6;
  int nw = (gridDim.x * blockDim.x) >> 6;
  float ss = 0.f;
  for (int i = wid; i < NU; i += nw) {
    float va = u_next[(size_t)i * DD + lane];
    float acc = uc[(size_t)i * DD + lane];
#pragma unroll
    for (int k = 0; k < 64; ++k) acc = fmaf(RDLANE_F(va, k), w[k], acc);
    users_raw[(size_t)i * DD + lane] = acc;
    ss += acc * acc;
  }
#pragma unroll
  for (int off = 32; off > 0; off >>= 1) ss += __shfl_xor(ss, off);
  if (lane == 0) atomicAdd(sumsq, ss);
}

__global__ void k_users_acc(const float* __restrict__ users_raw,
                            const float* __restrict__ sumsq, float* __restrict__ out_final) {
  float scale = 1.0f / sqrtf(*sumsq);
  int idx = blockIdx.x * blockDim.x + threadIdx.x;
  for (; idx < NU * DD; idx += gridDim.x * blockDim.x)
    out_final[idx] += users_raw[idx] * scale;
}

__global__ void k_scale(float* __restrict__ out_final) {
  int idx = blockIdx.x * blockDim.x + threadIdx.x;
  const int tot = NTOT * DD;
  for (; idx < tot; idx += gridDim.x * blockDim.x) out_final[idx] *= 0.25f;
}

extern "C" void kernel_launch(void* const* d_in, const int* in_sizes, int n_in,
                              void* d_out, int out_size, void* d_ws, size_t ws_size,
                              hipStream_t stream) {
  const float* u1      = (const float*)d_in[0];
  const float* u2      = (const float*)d_in[1];
  const float* item    = (const float*)d_in[2];
  const float* Wi      = (const float*)d_in[3];
  const float* Wc      = (const float*)d_in[4];
  const float* Ws      = (const float*)d_in[5];
  const float* fk_W    = (const float*)d_in[6];
  const float* fk_b    = (const float*)d_in[7];
  const float* A_vals  = (const float*)d_in[8];
  const float* A2_vals = (const float*)d_in[9];
  const float* S_vals  = (const float*)d_in[10];
  const int*   A_rows  = (const int*)d_in[11];
  const int*   A_cols  = (const int*)d_in[12];
  const int*   A2_rows = (const int*)d_in[13];
  const int*   A2_cols = (const int*)d_in[14];
  const int*   S_rows  = (const int*)d_in[15];
  const int*   S_cols  = (const int*)d_in[16];
  const int*   sh1     = (const int*)d_in[17];
  const int*   sh2     = (const int*)d_in[18];

  // ---- base workspace: 57,400,515 floats = 229.6 MB (proven-safe) ----
  float* ws   = (float*)d_ws;
  float* embA = ws;                              // 16,000,000 @ 0
  float* embB = embA + (size_t)NTOT * DD;        // 16,000,000 @ 16,000,000
  float* UC   = embB + (size_t)NTOT * DD;        // 6,400,000  @ 32,000,000
  float* n1   = UC + (size_t)NU * DD;            // 6,400,000  @ 38,400,000
  float* n2   = n1 + (size_t)NU * DD;            // 6,400,000  @ 44,800,000
  int2*  cvA  = (int2*)(n2 + (size_t)NU * DD);   // 2,000,000 int2 @ 51,200,000
  int2*  cvS  = cvA + NNZ_A;                     // 800,000 int2   @ 55,200,000
  int*   ptrA = (int*)(cvS + NNZ_S);             // 250,001 @ 56,800,000
  int*   ptrS = ptrA + (NTOT + 1);               // 100,001
  int*   cur  = ptrS + (NU + 1);                 // 250,000
  int*   bsum = cur + NTOT;                      // 256
  float* c1r  = (float*)(bsum + 256);            // 64
  float* c2r  = c1r + 64;
  float* w1   = c2r + 64;
  float* w2   = w1 + 64;
  float* sumsq = w2 + 64;                        // 1 -> end 57,400,515

  // cs1/cs2 live in the embB tail (rows [NU..), free until quad completes)
  int* cs1 = (int*)(embB + (size_t)NU * DD);     // 800,000 ints
  int* cs2 = cs1 + NNZ_S;                        // 800,000 ints

  // optional persistent A2 CSR (gated on actual ws_size; deterministic)
  bool persist = ws_size >= 246602100ULL;
  int2* cvA2  = (int2*)(ws + 57400516);
  int*  ptrA2 = (int*)(cvA2 + NNZ_A);

  float* out        = (float*)d_out;
  float* out_logits = out + (size_t)NTOT * DD;

  auto build = [&](const int* rows, const int* cols, const float* vals,
                   int n, int nnz, int* ptr, int2* cv) {
    int nb = (n + SCAN_CHUNK - 1) / SCAN_CHUNK;
    hipMemsetAsync(cur, 0, (size_t)n * sizeof(int), stream);
    k_hist<<<2048, 256, 0, stream>>>(rows, cur, nnz);
    k_scan1<<<nb, 256, 0, stream>>>(cur, bsum, n);
    k_scan2<<<1, 256, 0, stream>>>(bsum, nb);
    k_scan3<<<nb, 256, 0, stream>>>(cur, bsum, ptr, cur, n, nnz);
    k_scatter<<<2048, 256, 0, stream>>>(rows, cols, vals, cur, cv, nnz);
  };

  // ---------- CSR builds ----------
  build(S_rows, S_cols, S_vals, NU, NNZ_S, ptrS, cvS);
  k_mapcols<<<1024, 256, 0, stream>>>(cvS, sh1, sh2, cs1, cs2, NNZ_S);
  build(A_rows, A_cols, A_vals, NTOT, NNZ_A, ptrA, cvA);
  if (persist) build(A2_rows, A2_cols, A2_vals, NTOT, NNZ_A, ptrA2, cvA2);

  // ---------- init ----------
  hipMemsetAsync(c1r, 0, 128 * sizeof(float), stream);
  k_init<<<2048, 256, 0, stream>>>(u1, u2, item, embA, out);

  // ---------- quad S-SpMM: socials + layer-0 negs in one pass ----------
  // u1_soc -> UC, u2_soc -> embB[0:NU), n1_0 -> n1, n2_0 -> n2
  k_spmm_quadS<<<2048, 256, 0, stream>>>(ptrS, cvS, cs1, cs2, u1, u2, Wc,
                                         UC, embB, n1, n2);
  k_colsum2<<<256, 256, 0, stream>>>(UC, embB, c1r, c2r);
  k_wvec<<<1, 64, 0, stream>>>(fk_W, c1r, c2r, w1, w2);
  // slots 0-2: sc1=u2_soc.w1 rows[0,NU), sc2=u1_soc.w2 rows[NU,2NU); slot 3: layer-0 negs
  k_logits4<<<1024, 256, 0, stream>>>(UC, embB, n1, n2, w1, w2, fk_b, out_logits);
  // UC := (0.5*(u1_soc+u2_soc)) @ Ws[:,64:].T  (loop-invariant half of k_users)
  k_comb_gemm<<<1024, 256, 0, stream>>>(UC, embB, Ws);

  // ---------- layer loop ----------
  // negs: l=0 outputs in n1,n2; l=1 dual reads n1,n2 -> writes embB[0:2NU);
  //       l=2 dual reads embB[0:2NU) -> writes n1,n2 (before fusedA reuses embB)
  float* embCur = embA;
  float* embNext = embB;
  for (int l = 0; l < 3; ++l) {
    const int* pA; const int2* cA;
    if (l == 0)       { pA = ptrA;  cA = cvA;  }
    else if (persist) { pA = ptrA2; cA = cvA2; }
    else              { pA = ptrA;  cA = cvA;  }

    float* uraw;
    if (l == 0) {
      k_spmm_fusedA2<<<4096, 256, 0, stream>>>(pA, cA, embCur, Wi, embNext, out);
      if (!persist)
        build(A2_rows, A2_cols, A2_vals, NTOT, NNZ_A, ptrA, cvA);
      uraw = embCur;  // embA dead region
    } else if (l == 1) {
      k_spmm_fusedA2<<<4096, 256, 0, stream>>>(pA, cA, embCur, Wi, embNext, out);
      // dual: reads n1,n2 (layer-0 negs) -> writes embB[0:NU), embB[NU:2NU) + slot 4
      k_spmm_dualS<<<2048, 256, 0, stream>>>(ptrS, cvS, n1, n2, Wc,
          embCur, embCur + (size_t)NU * DD, w2, w1, fk_b, out_logits, 3 + l);
      uraw = n1;      // layer-0 negs dead after dual
    } else {
      // dual FIRST: reads embB negs (layer-1) -> writes n1,n2 + slot 5
      k_spmm_dualS<<<2048, 256, 0, stream>>>(ptrS, cvS,
          embNext, embNext + (size_t)NU * DD, Wc, n1, n2, w2, w1, fk_b,
          out_logits, 3 + l);
      k_spmm_fusedA2<<<4096, 256, 0, stream>>>(pA, cA, embCur, Wi, embNext, out);
      uraw = embCur;  // embA dead region
    }

    hipMemsetAsync(sumsq, 0, sizeof(float), stream);
    k_users<<<1024, 256, 0, stream>>>(embNext, UC, Ws, uraw, sumsq);
    k_users_acc<<<2048, 256, 0, stream>>>(uraw, sumsq, out);

    { float* t = embCur; embCur = embNext; embNext = t; }
  }

  k_scale<<<2048, 256, 0, stream>>>(out);
}